// Round 16
// baseline (571.064 us; speedup 1.0000x reference)
//
#include <hip/hip_runtime.h>
#include <climits>
#include <cstdint>

#define NV    2048
#define MAXE  344
#define HSIZE 8192
#define HMASK 8191
#define BIGK  LLONG_MAX
#define K3MAX 343
#define MAXP  256
#define PBUDGET (48ull*1024*1024)

typedef __attribute__((ext_vector_type(8))) short bf16x8;
typedef __attribute__((ext_vector_type(4))) float f32x4;

__device__ __forceinline__ unsigned hashk(long long k) {
  unsigned long long x = (unsigned long long)k * 0x9E3779B97F4A7C15ull;
  return (unsigned)(x >> 51) & HMASK;
}

__device__ __forceinline__ unsigned short bfr(float x) {   // fp32 -> bf16 RNE
  unsigned u = __float_as_uint(x);
  u = (u + 0x7FFFu + ((u >> 16) & 1u)) >> 16;
  return (unsigned short)u;
}

// ---------------- init + hash clear (fused) ----------------
__global__ __launch_bounds__(256) void k_init(const float* __restrict__ vf,
    const int* __restrict__ coors, int* __restrict__ cA, float* __restrict__ fA,
    int* __restrict__ nact, long long* __restrict__ hk, int* __restrict__ ocnt)
{
  const int bid = blockIdx.x;
  if (bid < 8) {
    const int i = bid * 256 + threadIdx.x;
    if (i == 0) { nact[0] = NV; nact[6] = 0; }
    if (i >= NV) return;
    cA[i*4+0] = coors[i*4+0];
    cA[i*4+1] = coors[i*4+1];
    cA[i*4+2] = coors[i*4+2];
    cA[i*4+3] = coors[i*4+3];
    fA[i] = vf[i];
  } else {
    const int i = (bid - 8) * 256 + threadIdx.x;
    if (i < HSIZE) hk[i] = -1LL;
    if (i < K3MAX) ocnt[i] = 0;
  }
}

__global__ __launch_bounds__(256) void k_hinsert(const int* __restrict__ c,
    long long* __restrict__ hk, int* __restrict__ hv, const int* __restrict__ nactp,
    int D, int H, int Wd)
{
  int i = blockIdx.x * 256 + threadIdx.x;
  if (i >= NV || i >= *nactp) return;
  long long key = (((long long)c[i*4+0]*D + c[i*4+1])*H + c[i*4+2])*(long long)Wd + c[i*4+3];
  unsigned h = hashk(key);
  while (true) {
    unsigned long long old = atomicCAS((unsigned long long*)&hk[h], ~0ull, (unsigned long long)key);
    if (old == ~0ull) { hv[h] = i; break; }
    h = (h + 1) & HMASK;
  }
}

// ---------------- neighbor hit lists + fused tail oscan + fused W transpose ----------------
// blocks [0, 512): hits + last-block oscan
// blocks [512, ...): W transpose, 32 out-cols x full-K slab per block
template<int K, int CIN, int C, bool DOWTR>
__global__ __launch_bounds__(256) void k_hits(const int* __restrict__ c,
    const long long* __restrict__ hk, const int* __restrict__ hv,
    const int* __restrict__ nactp, int* __restrict__ pslot, int* __restrict__ cnt,
    int* __restrict__ ocnt, int* __restrict__ olist, int* __restrict__ obase,
    int* __restrict__ done, int D, int H, int Wd,
    const float* __restrict__ Wa, const float* __restrict__ Wb,
    unsigned short* __restrict__ WtA, unsigned short* __restrict__ WtB)
{
  constexpr int K3 = K*K*K, R = K/2, CTR = K3/2;
  constexpr int NVB = NV / 4;
  __shared__ int s[512], s2[512];
  __shared__ int lastf;

  if (blockIdx.x >= NVB) {
    if constexpr (DOWTR) {
      __shared__ unsigned short tt[32][C + 24];
      constexpr int NCT = C / 32;
      constexpr int NBA = K3 * NCT;
      int b = blockIdx.x - NVB;
      const bool isA = (b < NBA);
      if (!isA) b -= NBA;
      const int o  = b / NCT;
      const int ct = b - o * NCT;
      const float* __restrict__ src = isA ? (Wa + (size_t)o * CIN * C)
                                          : (Wb + (size_t)o * C * C);
      unsigned short* __restrict__ dst = isA ? (WtA + (size_t)o * C * CIN)
                                             : (WtB + (size_t)o * C * C);
      const int nk = isA ? CIN : C;
      const int tid = threadIdx.x;
      const int kr = tid >> 3;            // k row (step 32)
      const int c4 = (tid & 7) * 4;       // col within 32-slab
      for (int k = kr; k < nk; k += 32) {
        const float4 v = *(const float4*)&src[(size_t)k * C + ct*32 + c4];
        tt[c4+0][k] = bfr(v.x);
        tt[c4+1][k] = bfr(v.y);
        tt[c4+2][k] = bfr(v.z);
        tt[c4+3][k] = bfr(v.w);
      }
      __syncthreads();
      const int cr = tid >> 3;            // out col row
      const int kq = (tid & 7) * 8;       // k chunk (8 ushorts = 16B)
      unsigned short* __restrict__ drow = dst + (size_t)(ct*32 + cr) * nk;
      for (int kb = 0; kb < nk; kb += 64) {
        const uint4 v = *(const uint4*)&tt[cr][kb + kq];
        *(uint4*)&drow[kb + kq] = v;
      }
    }
    return;
  }

  const int site = blockIdx.x * 4 + (threadIdx.x >> 6);
  const int lane = threadIdx.x & 63;
  const int nact = *nactp;
  if (site < nact) {
    const int b = c[site*4+0], d = c[site*4+1], hc = c[site*4+2], w = c[site*4+3];
    int base = 0;
    for (int o0 = 0; o0 < K3; o0 += 64) {
      const int o = o0 + lane;
      int j = -1;
      if (o < K3 && o != CTR) {
        const int dz = o/(K*K) - R, dy = (o/K)%K - R, dx = o%K - R;
        const int nd = d+dz, nh = hc+dy, nw = w+dx;
        if (nd >= 0 && nd < D && nh >= 0 && nh < H && nw >= 0 && nw < Wd) {
          const long long key = (((long long)b*D + nd)*H + nh)*(long long)Wd + nw;
          unsigned hs = hashk(key);
          while (true) {
            const long long kk = hk[hs];
            if (kk == -1LL) break;
            if (kk == key) { j = hv[hs]; break; }
            hs = (hs + 1) & HMASK;
          }
        }
      }
      const unsigned long long m = __ballot(j >= 0);
      if (j >= 0) {
        const int pos = __popcll(m & ((1ull << lane) - 1ull));
        const int p = atomicAdd(&ocnt[o], 1);
        int tag = -1;
        if (p < MAXP) { olist[o * MAXP + p] = (site << 12) | j; tag = (o << 8) | p; }
        pslot[site * MAXE + base + pos] = tag;
      }
      base += __popcll(m);
    }
    if (lane == 0) cnt[site] = base;
  } else if (lane == 0) cnt[site] = 0;

  __syncthreads();
  if (threadIdx.x == 0) {
    __threadfence();
    lastf = (atomicAdd(done, 1) == NVB - 1) ? 1 : 0;
  }
  __syncthreads();
  if (!lastf) return;
  const int t = threadIdx.x;
  const int v0 = (t < K3MAX) ? min(ocnt[t], MAXP) : 0;
  const int v1 = (t + 256 < K3MAX) ? min(ocnt[t + 256], MAXP) : 0;
  s[t] = v0; s[t + 256] = v1;
  __syncthreads();
  for (int d2 = 1; d2 < 512; d2 <<= 1) {
    s2[t]       = s[t]       + ((t >= d2)       ? s[t - d2]       : 0);
    s2[t + 256] = s[t + 256] + ((t + 256 >= d2) ? s[t + 256 - d2] : 0);
    __syncthreads();
    s[t] = s2[t]; s[t + 256] = s2[t + 256];
    __syncthreads();
  }
  if (t < K3MAX) obase[t] = s[t] - v0;
  if (t + 256 < K3MAX) obase[t + 256] = s[t + 256] - v1;
  if (t == 0) *done = 0;
}

// ---------------- MFMA bf16 fused center + per-offset gather GEMM ----------------
template<int CIN, int COUT>
__global__ __launch_bounds__(256) void k_mgemm(const float* __restrict__ f,
    const unsigned short* __restrict__ Wt, int ctr,
    float* __restrict__ outC, float* __restrict__ P,
    const int* __restrict__ ocnt, const int* __restrict__ obase,
    const int* __restrict__ olist)
{
  constexpr int BM = 32, BN = 128, KT = 32;
  constexpr int NCB = COUT / BN;
  constexpr int NRT = MAXP / BM;
  constexpr int NT  = CIN / KT;
  constexpr int NG  = (NV / BM) * NCB;
  constexpr int SLOTCAP = (int)(PBUDGET / ((size_t)COUT * 4));
  __shared__ unsigned short as2[BM][40];
  __shared__ unsigned short ws2[BN][40];

  const int tid  = threadIdx.x;
  const int wave = tid >> 6;
  const int lane = tid & 63;

  bool po;
  int row0, col0, m, sbase = 0, o = 0;
  if (blockIdx.x < NG) {
    po = false;
    const int rb = blockIdx.x / NCB, cb = blockIdx.x - rb * NCB;
    row0 = rb * BM; col0 = cb * BN; m = BM;
  } else {
    po = true;
    int bid = blockIdx.x - NG;
    o = bid / (NRT * NCB);
    int rem = bid - o * (NRT * NCB);
    const int rt = rem / NCB;
    const int cb = rem - rt * NCB;
    m = min(ocnt[o], MAXP);
    row0 = rt * BM;
    if (m == 0 || row0 >= m) return;
    sbase = obase[o]; col0 = cb * BN;
  }

  const int la_r = tid >> 3;
  const int la_k = (tid & 7) * 4;
  int grow;
  if (!po) grow = row0 + la_r;
  else { const int pA = row0 + la_r; grow = olist[o*MAXP + ((pA < m) ? pA : row0)] & 0xFFF; }
  const float* __restrict__ fA = f + (size_t)grow * CIN + la_k;

  const int wl_c = tid >> 1;
  const int wl_h = (tid & 1) * 16;
  const unsigned short* __restrict__ wbase =
      Wt + ((size_t)(po ? o : ctr) * COUT + col0 + wl_c) * CIN + wl_h;

  const int r0 = (wave & 1) * 16;
  const int c0 = (wave >> 1) * 64;
  const int lr = lane >> 4;
  const int lc = lane & 15;
  const int koff = lr * 8;

  f32x4 acc[4];
  #pragma unroll
  for (int fi = 0; fi < 4; ++fi) acc[fi] = (f32x4){0.f, 0.f, 0.f, 0.f};

  for (int t = 0; t < NT; ++t) {
    const int k0 = t * KT;
    {
      const float4 av = *(const float4*)&fA[k0];
      unsigned short* d = &as2[la_r][la_k];
      d[0] = bfr(av.x); d[1] = bfr(av.y); d[2] = bfr(av.z); d[3] = bfr(av.w);
      const uint4 w0 = *(const uint4*)&wbase[k0];
      const uint4 w1 = *(const uint4*)&wbase[k0 + 8];
      *(uint4*)&ws2[wl_c][wl_h]     = w0;
      *(uint4*)&ws2[wl_c][wl_h + 8] = w1;
    }
    __syncthreads();
    const bf16x8 a = *(const bf16x8*)&as2[r0 + lc][koff];
    #pragma unroll
    for (int fi = 0; fi < 4; ++fi) {
      const bf16x8 b = *(const bf16x8*)&ws2[c0 + fi*16 + lc][koff];
      acc[fi] = __builtin_amdgcn_mfma_f32_16x16x32_bf16(a, b, acc[fi], 0, 0, 0);
    }
    __syncthreads();
  }

  #pragma unroll
  for (int fi = 0; fi < 4; ++fi) {
    const int col = col0 + c0 + fi*16 + lc;
    #pragma unroll
    for (int i = 0; i < 4; ++i) {
      const int rloc = r0 + lr*4 + i;
      if (!po) {
        outC[(size_t)(row0 + rloc) * COUT + col] = acc[fi][i];
      } else {
        const int p = row0 + rloc;
        const int slot = sbase + p;
        if (p < m && slot < SLOTCAP)
          P[(size_t)slot * COUT + col] = acc[fi][i];
      }
    }
  }
}

// ---------------- fp32 fused GEMM (stage 0 conv-b only, C=64) ----------------
template<int CIN, int COUT>
__global__ __launch_bounds__(256) void k_cgemm(const float* __restrict__ f,
    const float* __restrict__ Wall, int ctr,
    float* __restrict__ outC, float* __restrict__ P,
    const int* __restrict__ ocnt, const int* __restrict__ obase,
    const int* __restrict__ olist)
{
  constexpr int BN = (COUT < 128) ? COUT : 128;
  constexpr int NQ = BN / 4;
  constexpr int TY = 256 / NQ;
  constexpr int BM = 32;
  constexpr int MR = BM / TY;
  constexpr int KT = 32;
  constexpr int NCB = COUT / BN;
  constexpr int NRT = MAXP / BM;
  constexpr int NT_C = CIN / KT;
  constexpr int NG = (NV / BM) * NCB;
  constexpr int WLPT = (KT * NQ) / 256;
  constexpr int SLOTCAP = (int)(PBUDGET / ((size_t)COUT * 4));
  __shared__ float as[BM][KT + 1];
  __shared__ float ws[KT][BN];

  const int tid = threadIdx.x;
  const int cq = tid % NQ;
  const int ty = tid / NQ;
  const int la_r = tid >> 3;
  const int la_q = tid & 7;

  bool po;
  int row0, col0, m, sbase = 0, o = 0;
  if (blockIdx.x < NG) {
    po = false;
    const int rb = blockIdx.x / NCB, cb = blockIdx.x - rb * NCB;
    row0 = rb * BM; col0 = cb * BN; m = BM;
  } else {
    po = true;
    int bid = blockIdx.x - NG;
    o = bid / (NRT * NCB);
    int rem = bid - o * (NRT * NCB);
    const int rt = rem / NCB;
    const int cb = rem - rt * NCB;
    m = min(ocnt[o], MAXP);
    row0 = rt * BM;
    if (m == 0 || row0 >= m) return;
    sbase = obase[o]; col0 = cb * BN;
  }

  const float* __restrict__ fW = Wall + (size_t)(po ? o : ctr) * (CIN*COUT) + col0;
  int grow;
  if (!po) grow = row0 + la_r;
  else { const int pA = row0 + la_r; grow = olist[o*MAXP + ((pA < m) ? pA : row0)] & 0xFFF; }
  const float* __restrict__ fA = f + (size_t)grow * CIN + la_q * 4;

  float4 aP, wP[WLPT];
  aP = *(const float4*)&fA[0];
  #pragma unroll
  for (int i = 0; i < WLPT; ++i) {
    const int idx = tid + i*256, k = idx / NQ, q = idx - k*NQ;
    wP[i] = *(const float4*)&fW[(size_t)k * COUT + q*4];
  }

  float4 acc[MR];
  #pragma unroll
  for (int i = 0; i < MR; ++i) { acc[i].x=0.f; acc[i].y=0.f; acc[i].z=0.f; acc[i].w=0.f; }

  for (int t = 0; t < NT_C; ++t) {
    as[la_r][la_q*4+0] = aP.x;
    as[la_r][la_q*4+1] = aP.y;
    as[la_r][la_q*4+2] = aP.z;
    as[la_r][la_q*4+3] = aP.w;
    #pragma unroll
    for (int i = 0; i < WLPT; ++i) {
      const int idx = tid + i*256, k = idx / NQ, q = idx - k*NQ;
      *(float4*)&ws[k][q*4] = wP[i];
    }
    __syncthreads();
    if (t + 1 < NT_C) {
      const int k0 = (t + 1) * KT;
      aP = *(const float4*)&fA[k0];
      #pragma unroll
      for (int i = 0; i < WLPT; ++i) {
        const int idx = tid + i*256, k = idx / NQ, q = idx - k*NQ;
        wP[i] = *(const float4*)&fW[(size_t)(k0 + k) * COUT + q*4];
      }
    }
    #pragma unroll
    for (int k = 0; k < KT; ++k) {
      const float4 wv = *(const float4*)&ws[k][cq*4];
      #pragma unroll
      for (int i = 0; i < MR; ++i) {
        const float av = as[ty*MR + i][k];
        acc[i].x = fmaf(av, wv.x, acc[i].x);
        acc[i].y = fmaf(av, wv.y, acc[i].y);
        acc[i].z = fmaf(av, wv.z, acc[i].z);
        acc[i].w = fmaf(av, wv.w, acc[i].w);
      }
    }
    __syncthreads();
  }
  if (!po) {
    #pragma unroll
    for (int i = 0; i < MR; ++i)
      *(float4*)&outC[(size_t)(row0 + ty*MR + i) * COUT + col0 + cq*4] = acc[i];
  } else {
    #pragma unroll
    for (int i = 0; i < MR; ++i) {
      const int p = row0 + ty*MR + i;
      const int slot = sbase + p;
      if (p < m && slot < SLOTCAP)
        *(float4*)&P[(size_t)slot * COUT + col0 + cq*4] = acc[i];
    }
  }
}

// ---------------- stage-0 conv-a (CIN==1) ----------------
template<int COUT>
__global__ __launch_bounds__(256) void k_cgemm1(const float* __restrict__ f,
    const float* __restrict__ Wall, int ctr,
    float* __restrict__ outC, float* __restrict__ P,
    const int* __restrict__ ocnt, const int* __restrict__ obase,
    const int* __restrict__ olist)
{
  constexpr int NG = NV * COUT / 256;
  constexpr int SLOTCAP = (int)(PBUDGET / ((size_t)COUT * 4));
  const int tid = threadIdx.x;
  if (blockIdx.x < NG) {
    const int idx = blockIdx.x * 256 + tid;
    const int i = idx / COUT, c = idx - i * COUT;
    outC[idx] = f[i] * Wall[(size_t)ctr * COUT + c];
  } else {
    const int o = blockIdx.x - NG;
    int m = ocnt[o];
    if (m == 0) return;
    if (m > MAXP) m = MAXP;
    const int sbase = obase[o];
    const float* __restrict__ Wo = Wall + (size_t)o * COUT;
    for (int p = 0; p < m; ++p) {
      const int j = olist[o*MAXP + p] & 0xFFF;
      const int slot = sbase + p;
      if (slot < SLOTCAP && tid < COUT)
        P[(size_t)slot*COUT + tid] = f[j] * Wo[tid];
    }
  }
}

// ---------------- fused psum + BN stats + BN-ReLU (+ hash duties) ----------------
template<int COUT, bool POOL>
__global__ __launch_bounds__(256) void k_bn(float* __restrict__ x,
    const float* __restrict__ P, const int* __restrict__ pslot,
    const int* __restrict__ obase, const int* __restrict__ cnt,
    const float* __restrict__ g, const float* __restrict__ b,
    const int* __restrict__ nactp,
    const int* __restrict__ co, long long* __restrict__ pk, float* __restrict__ fY,
    long long* __restrict__ hk, int* __restrict__ hv,
    int sd, int sh, int sw, int oD, int oH, int oW)
{
  constexpr int RPT = NV / 256;
  constexpr int SLOTCAP = (int)(PBUDGET / ((size_t)COUT * 4));
  const int c = blockIdx.x;
  const int tid = threadIdx.x;
  const int nact = *nactp;

  if (!POOL && c < 32) {
    const int i = c * 256 + tid;
    hk[i] = -1LL;
    hv[i] = INT_MAX;
  }
  if (POOL && c < 8) {
    const int i = c * 256 + tid;
    if (i < nact) {
      const int bb = co[i*4+0];
      const int d = co[i*4+1] / sd, h = co[i*4+2] / sh, w = co[i*4+3] / sw;
      const long long key = (((long long)bb*oD + d)*oH + h)*(long long)oW + w;
      pk[i] = key;
      unsigned hs = hashk(key);
      while (true) {
        unsigned long long old = atomicCAS((unsigned long long*)&hk[hs], ~0ull, (unsigned long long)key);
        if (old == ~0ull || (long long)old == key) { atomicMin(&hv[hs], i); break; }
        hs = (hs + 1) & HMASK;
      }
    } else pk[i] = BIGK;
  }

  float v[RPT];
  double s1 = 0.0, s2 = 0.0;
  #pragma unroll
  for (int rr = 0; rr < RPT; ++rr) {
    const int r = rr * 256 + tid;
    float vv = x[(size_t)r * COUT + c];
    if (r < nact) {
      const int n = cnt[r];
      float acc = 0.f;
      for (int h = 0; h < n; ++h) {
        const int e = pslot[r * MAXE + h];
        if (e < 0) continue;
        const int slot = obase[e >> 8] + (e & 0xFF);
        if (slot >= SLOTCAP) continue;
        acc += P[(size_t)slot * COUT + c];
      }
      vv += acc;
    }
    v[rr] = vv;
    s1 += (double)vv;
    s2 += (double)vv * (double)vv;
  }
  __shared__ double r1[256], r2[256];
  __shared__ float ss[2];
  r1[tid] = s1; r2[tid] = s2;
  __syncthreads();
  for (int off = 128; off > 0; off >>= 1) {
    if (tid < off) { r1[tid] += r1[tid + off]; r2[tid] += r2[tid + off]; }
    __syncthreads();
  }
  if (tid == 0) {
    const double n = (double)nact;
    const double mu = r1[0] / n;
    double var = r2[0] / n - mu * mu;
    if (var < 0.0) var = 0.0;
    const double sc = (double)g[c] / sqrt(var + 1e-4);
    ss[0] = (float)sc;
    ss[1] = (float)((double)b[c] - mu * sc);
  }
  __syncthreads();
  const float scale = ss[0], shift = ss[1];
  #pragma unroll
  for (int rr = 0; rr < RPT; ++rr) {
    const int r = rr * 256 + tid;
    float o_ = 0.f;
    if (r < nact) {
      const float y = fmaf(v[rr], scale, shift);
      o_ = (y > 0.f) ? y : 0.f;
    }
    x[(size_t)r * COUT + c] = o_;
    if (POOL) fY[(size_t)r * COUT + c] = 0.f;
  }
}

// ---------------- pool compaction: hash-winner (min site) + prefix-scan rank ----------------
__global__ __launch_bounds__(1024) void k_pcompact(const long long* __restrict__ pk,
    const long long* __restrict__ hk, const int* __restrict__ hv,
    int* __restrict__ cNew, int* __restrict__ map, int* __restrict__ nactOut,
    int D, int H, int Wd)
{
  __shared__ int flag[NV];
  __shared__ int s2[NV];
  __shared__ int rankArr[NV];
  const int t = threadIdx.x;
  const long long k0 = pk[t], k1 = pk[t + 1024];
  int w0 = -1, w1 = -1;
  if (k0 != BIGK) { unsigned h = hashk(k0); while (hk[h] != k0) h = (h + 1) & HMASK; w0 = hv[h]; }
  if (k1 != BIGK) { unsigned h = hashk(k1); while (hk[h] != k1) h = (h + 1) & HMASK; w1 = hv[h]; }
  flag[t] = (w0 == t);
  flag[t + 1024] = (w1 == t + 1024);
  __syncthreads();
  for (int d2 = 1; d2 < NV; d2 <<= 1) {
    s2[t]        = flag[t]        + ((t >= d2)        ? flag[t - d2]        : 0);
    s2[t + 1024] = flag[t + 1024] + ((t + 1024 >= d2) ? flag[t + 1024 - d2] : 0);
    __syncthreads();
    flag[t] = s2[t]; flag[t + 1024] = s2[t + 1024];
    __syncthreads();
  }
  if (w0 == t) rankArr[t] = flag[t] - 1;
  if (w1 == t + 1024) rankArr[t + 1024] = flag[t + 1024] - 1;
  __syncthreads();
  if (k0 != BIGK) {
    const int r = rankArr[w0];
    map[t] = r;
    if (w0 == t) {
      const int w = (int)(k0 % Wd);
      long long q = k0 / Wd;
      const int h = (int)(q % H); q /= H;
      const int d = (int)(q % D);
      const int b = (int)(q / D);
      cNew[r*4+0] = b; cNew[r*4+1] = d; cNew[r*4+2] = h; cNew[r*4+3] = w;
    }
  }
  if (k1 != BIGK) {
    const int r = rankArr[w1];
    map[t + 1024] = r;
    if (w1 == t + 1024) {
      const int w = (int)(k1 % Wd);
      long long q = k1 / Wd;
      const int h = (int)(q % H); q /= H;
      const int d = (int)(q % D);
      const int b = (int)(q / D);
      cNew[r*4+0] = b; cNew[r*4+1] = d; cNew[r*4+2] = h; cNew[r*4+3] = w;
    }
  }
  if (t == 0) *nactOut = flag[NV - 1];
}

// ---------------- fused pool-scatter + next-stage hash clear ----------------
template<int C>
__global__ __launch_bounds__(256) void k_pscl(const float* __restrict__ src,
    float* __restrict__ dst, const int* __restrict__ map, const int* __restrict__ nactp,
    long long* __restrict__ hk, int* __restrict__ ocnt)
{
  constexpr int GPS = NV * C / 256;
  if (blockIdx.x < GPS) {
    const int idx = blockIdx.x * 256 + threadIdx.x;
    const int i = idx / C;
    if (i >= *nactp) return;
    atomicMax((unsigned*)&dst[map[i] * C + (idx % C)], __float_as_uint(src[idx]));
  } else {
    const int i = (blockIdx.x - GPS) * 256 + threadIdx.x;
    if (i < HSIZE) hk[i] = -1LL;
    if (i < K3MAX) ocnt[i] = 0;
  }
}

// ---------------- output zero (float4 grid-stride) ----------------
__global__ __launch_bounds__(256) void k_zero_out(float4* __restrict__ out, int n4)
{
  const int stride = gridDim.x * 256;
  float4 z; z.x = 0.f; z.y = 0.f; z.z = 0.f; z.w = 0.f;
  for (int i = blockIdx.x * 256 + threadIdx.x; i < n4; i += stride)
    out[i] = z;
}

// ---------------- final dense scatter ----------------
__global__ __launch_bounds__(256) void k_out(const float* __restrict__ f,
    const int* __restrict__ c, float* __restrict__ out, const int* __restrict__ nactp)
{
  const int idx = blockIdx.x * 256 + threadIdx.x;
  const int i = idx >> 9, ch = idx & 511;
  if (i >= *nactp) return;
  const int b = c[i*4+0], d = c[i*4+1], h = c[i*4+2], w = c[i*4+3];
  out[ (((b*512 + ch)*2 + d)*111 + h)*98 + w ] = f[idx];
}

// ---------------- host orchestration ----------------
template<int K, int CIN, int C>
static void run_stage(hipStream_t stream, int s,
    const float* Wa, const float* Ga, const float* Ba,
    const float* Wb, const float* Gb, const float* Bb,
    float* fX, float* fY, int* cX, int* cY,
    int D, int H, int W, int pd, int ph, int pw, int oD, int oH, int oW,
    long long* hk, int* hv, long long* pkey, int* pslot, int* cnt, int* map,
    int* nact, int* ocnt, int* obase, int* olist, float* P, unsigned short* Wt)
{
  constexpr int K3 = K*K*K;
  constexpr int CTR = K3/2;
  constexpr int NRT  = MAXP / 32;
  const int* na = nact + s;
  int* done = nact + 6;

  k_hinsert<<<NV/256, 256, 0, stream>>>(cX, hk, hv, na, D, H, W);

  if constexpr (C >= 128) {
    constexpr int NCB = C / 128;
    constexpr int NG  = (NV / 32) * NCB;
    constexpr int NWT = K3 * 2 * (C / 32);
    unsigned short* WtB = Wt + (size_t)K3 * C * CIN;
    k_hits<K, CIN, C, true><<<NV/4 + NWT, 256, 0, stream>>>(cX, hk, hv, na, pslot, cnt,
        ocnt, olist, obase, done, D, H, W, Wa, Wb, Wt, WtB);
    k_mgemm<CIN, C><<<NG + K3*NRT*NCB, 256, 0, stream>>>(fX, Wt, CTR, fY, P, ocnt, obase, olist);
    k_bn<C, false><<<C, 256, 0, stream>>>(fY, P, pslot, obase, cnt, Ga, Ba, na,
        cX, pkey, fX, hk, hv, pd, ph, pw, oD, oH, oW);
    k_mgemm<C, C><<<NG + K3*NRT*NCB, 256, 0, stream>>>(fY, WtB, CTR, fX, P, ocnt, obase, olist);
    k_bn<C, true><<<C, 256, 0, stream>>>(fX, P, pslot, obase, cnt, Gb, Bb, na,
        cX, pkey, fY, hk, hv, pd, ph, pw, oD, oH, oW);
  } else {
    k_hits<K, CIN, C, false><<<NV/4, 256, 0, stream>>>(cX, hk, hv, na, pslot, cnt,
        ocnt, olist, obase, done, D, H, W, nullptr, nullptr, nullptr, nullptr);
    k_cgemm1<C><<<NV*C/256 + K3, 256, 0, stream>>>(fX, Wa, CTR, fY, P, ocnt, obase, olist);
    k_bn<C, false><<<C, 256, 0, stream>>>(fY, P, pslot, obase, cnt, Ga, Ba, na,
        cX, pkey, fX, hk, hv, pd, ph, pw, oD, oH, oW);
    k_cgemm<C, C><<<(NV/32) + K3*NRT, 256, 0, stream>>>(fY, Wb, CTR, fX, P, ocnt, obase, olist);
    k_bn<C, true><<<C, 256, 0, stream>>>(fX, P, pslot, obase, cnt, Gb, Bb, na,
        cX, pkey, fY, hk, hv, pd, ph, pw, oD, oH, oW);
  }

  k_pcompact<<<1, 1024, 0, stream>>>(pkey, hk, hv, cY, map, nact + s + 1, oD, oH, oW);
  k_pscl<C><<<NV*C/256 + HSIZE/256, 256, 0, stream>>>(fX, fY, map, na, hk, ocnt);
}

extern "C" void kernel_launch(void* const* d_in, const int* in_sizes, int n_in,
                              void* d_out, int out_size, void* d_ws, size_t ws_size,
                              hipStream_t stream)
{
  const float* vf    = (const float*)d_in[0];
  const int*   coors = (const int*)d_in[1];
  const float *Wl[10], *Gl[10], *Bl[10];
  for (int i = 0; i < 10; ++i) {
    Wl[i] = (const float*)d_in[3 + 3*i];
    Gl[i] = (const float*)d_in[4 + 3*i];
    Bl[i] = (const float*)d_in[5 + 3*i];
  }

  char* p = (char*)d_ws;
  auto alloc = [&](size_t bytes) { char* q = p; p += (bytes + 255) & ~(size_t)255; return q; };
  float*     fB    = (float*)    alloc((size_t)NV*512*4);
  long long* hk    = (long long*)alloc((size_t)HSIZE*8);
  long long* pkey  = (long long*)alloc((size_t)NV*8);
  int*       hv    = (int*)      alloc((size_t)HSIZE*4);
  int*       cA    = (int*)      alloc((size_t)NV*4*4);
  int*       cB    = (int*)      alloc((size_t)NV*4*4);
  int*       pslot = (int*)      alloc((size_t)NV*MAXE*4);
  int*       cnt   = (int*)      alloc((size_t)NV*4);
  int*       map   = (int*)      alloc((size_t)NV*4);
  int*       nact  = (int*)      alloc(8*4);
  int*       ocnt  = (int*)      alloc((size_t)K3MAX*4);
  int*       obase = (int*)      alloc((size_t)K3MAX*4);

  // scratch aliased into d_out (89 MB); all dead before the final zero
  float*          fA    = (float*)d_out;                                    // 4 MB
  int*            olist = (int*)   ((char*)d_out + (size_t)8*1024*1024);    // 351 KB
  unsigned short* Wt    = (unsigned short*)((char*)d_out + (size_t)9*1024*1024);  // 32 MB
  float*          P     = (float*) ((char*)d_out + (size_t)41*1024*1024);   // 48 MB (SLOTCAP-guarded)

  k_init<<<40, 256, 0, stream>>>(vf, coors, cA, fA, nact, hk, ocnt);

  run_stage<7, 1, 64>  (stream, 0, Wl[0],Gl[0],Bl[0], Wl[1],Gl[1],Bl[1],
    fA, fB, cA, cB, 216, 7992, 7056, 3, 3, 3, 72, 2664, 2352,
    hk, hv, pkey, pslot, cnt, map, nact, ocnt, obase, olist, P, Wt);
  run_stage<7, 64, 128>(stream, 1, Wl[2],Gl[2],Bl[2], Wl[3],Gl[3],Bl[3],
    fB, fA, cB, cA, 72, 2664, 2352, 3, 3, 3, 24, 888, 784,
    hk, hv, pkey, pslot, cnt, map, nact, ocnt, obase, olist, P, Wt);
  run_stage<5, 128, 256>(stream, 2, Wl[4],Gl[4],Bl[4], Wl[5],Gl[5],Bl[5],
    fA, fB, cA, cB, 24, 888, 784, 3, 2, 2, 8, 444, 392,
    hk, hv, pkey, pslot, cnt, map, nact, ocnt, obase, olist, P, Wt);
  run_stage<3, 256, 384>(stream, 3, Wl[6],Gl[6],Bl[6], Wl[7],Gl[7],Bl[7],
    fB, fA, cB, cA, 8, 444, 392, 2, 2, 2, 4, 222, 196,
    hk, hv, pkey, pslot, cnt, map, nact, ocnt, obase, olist, P, Wt);
  run_stage<3, 384, 512>(stream, 4, Wl[8],Gl[8],Bl[8], Wl[9],Gl[9],Bl[9],
    fA, fB, cA, cB, 4, 222, 196, 2, 2, 2, 2, 111, 98,
    hk, hv, pkey, pslot, cnt, map, nact, ocnt, obase, olist, P, Wt);

  k_zero_out<<<2048, 256, 0, stream>>>((float4*)d_out, out_size / 4);
  k_out<<<NV*512/256, 256, 0, stream>>>(fB, cB, (float*)d_out, nact + 5);
}

// Round 17
// 561.286 us; speedup vs baseline: 1.0174x; 1.0174x over previous
//
#include <hip/hip_runtime.h>
#include <climits>
#include <cstdint>

#define NV    2048
#define MAXE  344
#define HSIZE 8192
#define HMASK 8191
#define BIGK  LLONG_MAX
#define K3MAX 343
#define MAXP  256
#define PBUDGET (48ull*1024*1024)

typedef __attribute__((ext_vector_type(8))) short bf16x8;
typedef __attribute__((ext_vector_type(4))) float f32x4;

__device__ __forceinline__ unsigned hashk(long long k) {
  unsigned long long x = (unsigned long long)k * 0x9E3779B97F4A7C15ull;
  return (unsigned)(x >> 51) & HMASK;
}

__device__ __forceinline__ unsigned short bfr(float x) {   // fp32 -> bf16 RNE
  unsigned u = __float_as_uint(x);
  u = (u + 0x7FFFu + ((u >> 16) & 1u)) >> 16;
  return (unsigned short)u;
}

// ---------------- init + hash clear (fused) ----------------
__global__ __launch_bounds__(256) void k_init(const float* __restrict__ vf,
    const int* __restrict__ coors, int* __restrict__ cA, float* __restrict__ fA,
    int* __restrict__ nact, long long* __restrict__ hk, int* __restrict__ ocnt)
{
  const int bid = blockIdx.x;
  if (bid < 8) {
    const int i = bid * 256 + threadIdx.x;
    if (i == 0) { nact[0] = NV; nact[6] = 0; }
    if (i >= NV) return;
    cA[i*4+0] = coors[i*4+0];
    cA[i*4+1] = coors[i*4+1];
    cA[i*4+2] = coors[i*4+2];
    cA[i*4+3] = coors[i*4+3];
    fA[i] = vf[i];
  } else {
    const int i = (bid - 8) * 256 + threadIdx.x;
    if (i < HSIZE) hk[i] = -1LL;
    if (i < K3MAX) ocnt[i] = 0;
  }
}

__global__ __launch_bounds__(256) void k_hinsert(const int* __restrict__ c,
    long long* __restrict__ hk, int* __restrict__ hv, const int* __restrict__ nactp,
    int D, int H, int Wd)
{
  int i = blockIdx.x * 256 + threadIdx.x;
  if (i >= NV || i >= *nactp) return;
  long long key = (((long long)c[i*4+0]*D + c[i*4+1])*H + c[i*4+2])*(long long)Wd + c[i*4+3];
  unsigned h = hashk(key);
  while (true) {
    unsigned long long old = atomicCAS((unsigned long long*)&hk[h], ~0ull, (unsigned long long)key);
    if (old == ~0ull) { hv[h] = i; break; }
    h = (h + 1) & HMASK;
  }
}

// ---------------- W transpose slab: compile-time NK -> fully unrolled, ILP loads ----------------
template<int NK, int CC>
__device__ __forceinline__ void wslab(const float* __restrict__ src,
    unsigned short* __restrict__ dst, int ct, int tid,
    unsigned short (*__restrict__ tt)[CC + 24])
{
  const int kr = tid >> 3;
  const int c4 = (tid & 7) * 4;
  #pragma unroll
  for (int i = 0; i < NK/32; ++i) {
    const int k = kr + i*32;
    const float4 v = *(const float4*)&src[(size_t)k * CC + ct*32 + c4];
    tt[c4+0][k] = bfr(v.x);
    tt[c4+1][k] = bfr(v.y);
    tt[c4+2][k] = bfr(v.z);
    tt[c4+3][k] = bfr(v.w);
  }
  __syncthreads();
  const int cr = tid >> 3;
  const int kq = (tid & 7) * 8;
  unsigned short* __restrict__ drow = dst + (size_t)(ct*32 + cr) * NK;
  #pragma unroll
  for (int kb = 0; kb < NK; kb += 64) {
    const uint4 v = *(const uint4*)&tt[cr][kb + kq];
    *(uint4*)&drow[kb + kq] = v;
  }
}

// ---------------- neighbor hit lists + fused tail oscan + fused W transpose ----------------
template<int K, int CIN, int C, bool DOWTR>
__global__ __launch_bounds__(256) void k_hits(const int* __restrict__ c,
    const long long* __restrict__ hk, const int* __restrict__ hv,
    const int* __restrict__ nactp, int* __restrict__ pslot, int* __restrict__ cnt,
    int* __restrict__ ocnt, int* __restrict__ olist, int* __restrict__ obase,
    int* __restrict__ done, int D, int H, int Wd,
    const float* __restrict__ Wa, const float* __restrict__ Wb,
    unsigned short* __restrict__ WtA, unsigned short* __restrict__ WtB)
{
  constexpr int K3 = K*K*K, R = K/2, CTR = K3/2;
  constexpr int NVB = NV / 4;
  __shared__ int s[512], s2[512];
  __shared__ int lastf;

  if (blockIdx.x >= NVB) {
    if constexpr (DOWTR) {
      __shared__ unsigned short tt[32][C + 24];
      constexpr int NCT = C / 32;
      constexpr int NBA = K3 * NCT;
      int b = blockIdx.x - NVB;
      const bool isA = (b < NBA);
      if (!isA) b -= NBA;
      const int o  = b / NCT;
      const int ct = b - o * NCT;
      const int tid = threadIdx.x;
      if (isA)
        wslab<CIN, C>(Wa + (size_t)o * CIN * C, WtA + (size_t)o * C * CIN, ct, tid, tt);
      else
        wslab<C, C>(Wb + (size_t)o * C * C, WtB + (size_t)o * C * C, ct, tid, tt);
    }
    return;
  }

  const int site = blockIdx.x * 4 + (threadIdx.x >> 6);
  const int lane = threadIdx.x & 63;
  const int nact = *nactp;
  if (site < nact) {
    const int b = c[site*4+0], d = c[site*4+1], hc = c[site*4+2], w = c[site*4+3];
    int base = 0;
    for (int o0 = 0; o0 < K3; o0 += 64) {
      const int o = o0 + lane;
      int j = -1;
      if (o < K3 && o != CTR) {
        const int dz = o/(K*K) - R, dy = (o/K)%K - R, dx = o%K - R;
        const int nd = d+dz, nh = hc+dy, nw = w+dx;
        if (nd >= 0 && nd < D && nh >= 0 && nh < H && nw >= 0 && nw < Wd) {
          const long long key = (((long long)b*D + nd)*H + nh)*(long long)Wd + nw;
          unsigned hs = hashk(key);
          while (true) {
            const long long kk = hk[hs];
            if (kk == -1LL) break;
            if (kk == key) { j = hv[hs]; break; }
            hs = (hs + 1) & HMASK;
          }
        }
      }
      const unsigned long long m = __ballot(j >= 0);
      if (j >= 0) {
        const int pos = __popcll(m & ((1ull << lane) - 1ull));
        const int p = atomicAdd(&ocnt[o], 1);
        int tag = -1;
        if (p < MAXP) { olist[o * MAXP + p] = (site << 12) | j; tag = (o << 8) | p; }
        pslot[site * MAXE + base + pos] = tag;
      }
      base += __popcll(m);
    }
    if (lane == 0) cnt[site] = base;
  } else if (lane == 0) cnt[site] = 0;

  __syncthreads();
  if (threadIdx.x == 0) {
    __threadfence();
    lastf = (atomicAdd(done, 1) == NVB - 1) ? 1 : 0;
  }
  __syncthreads();
  if (!lastf) return;
  const int t = threadIdx.x;
  const int v0 = (t < K3MAX) ? min(ocnt[t], MAXP) : 0;
  const int v1 = (t + 256 < K3MAX) ? min(ocnt[t + 256], MAXP) : 0;
  s[t] = v0; s[t + 256] = v1;
  __syncthreads();
  for (int d2 = 1; d2 < 512; d2 <<= 1) {
    s2[t]       = s[t]       + ((t >= d2)       ? s[t - d2]       : 0);
    s2[t + 256] = s[t + 256] + ((t + 256 >= d2) ? s[t + 256 - d2] : 0);
    __syncthreads();
    s[t] = s2[t]; s[t + 256] = s2[t + 256];
    __syncthreads();
  }
  if (t < K3MAX) obase[t] = s[t] - v0;
  if (t + 256 < K3MAX) obase[t + 256] = s[t + 256] - v1;
  if (t == 0) *done = 0;
}

// ---------------- MFMA bf16 fused center + per-offset gather GEMM ----------------
template<int CIN, int COUT>
__global__ __launch_bounds__(256) void k_mgemm(const float* __restrict__ f,
    const unsigned short* __restrict__ Wt, int ctr,
    float* __restrict__ outC, float* __restrict__ P,
    const int* __restrict__ ocnt, const int* __restrict__ obase,
    const int* __restrict__ olist)
{
  constexpr int BM = 32, BN = 128, KT = 32;
  constexpr int NCB = COUT / BN;
  constexpr int NRT = MAXP / BM;
  constexpr int NT  = CIN / KT;
  constexpr int NG  = (NV / BM) * NCB;
  constexpr int SLOTCAP = (int)(PBUDGET / ((size_t)COUT * 4));
  __shared__ unsigned short as2[BM][40];
  __shared__ unsigned short ws2[BN][40];

  const int tid  = threadIdx.x;
  const int wave = tid >> 6;
  const int lane = tid & 63;

  bool po;
  int row0, col0, m, sbase = 0, o = 0;
  if (blockIdx.x < NG) {
    po = false;
    const int rb = blockIdx.x / NCB, cb = blockIdx.x - rb * NCB;
    row0 = rb * BM; col0 = cb * BN; m = BM;
  } else {
    po = true;
    int bid = blockIdx.x - NG;
    o = bid / (NRT * NCB);
    int rem = bid - o * (NRT * NCB);
    const int rt = rem / NCB;
    const int cb = rem - rt * NCB;
    m = min(ocnt[o], MAXP);
    row0 = rt * BM;
    if (m == 0 || row0 >= m) return;
    sbase = obase[o]; col0 = cb * BN;
  }

  const int la_r = tid >> 3;
  const int la_k = (tid & 7) * 4;
  int grow;
  if (!po) grow = row0 + la_r;
  else { const int pA = row0 + la_r; grow = olist[o*MAXP + ((pA < m) ? pA : row0)] & 0xFFF; }
  const float* __restrict__ fA = f + (size_t)grow * CIN + la_k;

  const int wl_c = tid >> 1;
  const int wl_h = (tid & 1) * 16;
  const unsigned short* __restrict__ wbase =
      Wt + ((size_t)(po ? o : ctr) * COUT + col0 + wl_c) * CIN + wl_h;

  const int r0 = (wave & 1) * 16;
  const int c0 = (wave >> 1) * 64;
  const int lr = lane >> 4;
  const int lc = lane & 15;
  const int koff = lr * 8;

  f32x4 acc[4];
  #pragma unroll
  for (int fi = 0; fi < 4; ++fi) acc[fi] = (f32x4){0.f, 0.f, 0.f, 0.f};

  for (int t = 0; t < NT; ++t) {
    const int k0 = t * KT;
    {
      const float4 av = *(const float4*)&fA[k0];
      unsigned short* d = &as2[la_r][la_k];
      d[0] = bfr(av.x); d[1] = bfr(av.y); d[2] = bfr(av.z); d[3] = bfr(av.w);
      const uint4 w0 = *(const uint4*)&wbase[k0];
      const uint4 w1 = *(const uint4*)&wbase[k0 + 8];
      *(uint4*)&ws2[wl_c][wl_h]     = w0;
      *(uint4*)&ws2[wl_c][wl_h + 8] = w1;
    }
    __syncthreads();
    const bf16x8 a = *(const bf16x8*)&as2[r0 + lc][koff];
    #pragma unroll
    for (int fi = 0; fi < 4; ++fi) {
      const bf16x8 b = *(const bf16x8*)&ws2[c0 + fi*16 + lc][koff];
      acc[fi] = __builtin_amdgcn_mfma_f32_16x16x32_bf16(a, b, acc[fi], 0, 0, 0);
    }
    __syncthreads();
  }

  #pragma unroll
  for (int fi = 0; fi < 4; ++fi) {
    const int col = col0 + c0 + fi*16 + lc;
    #pragma unroll
    for (int i = 0; i < 4; ++i) {
      const int rloc = r0 + lr*4 + i;
      if (!po) {
        outC[(size_t)(row0 + rloc) * COUT + col] = acc[fi][i];
      } else {
        const int p = row0 + rloc;
        const int slot = sbase + p;
        if (p < m && slot < SLOTCAP)
          P[(size_t)slot * COUT + col] = acc[fi][i];
      }
    }
  }
}

// ---------------- fp32 fused GEMM (stage 0 conv-b only, C=64) ----------------
template<int CIN, int COUT>
__global__ __launch_bounds__(256) void k_cgemm(const float* __restrict__ f,
    const float* __restrict__ Wall, int ctr,
    float* __restrict__ outC, float* __restrict__ P,
    const int* __restrict__ ocnt, const int* __restrict__ obase,
    const int* __restrict__ olist)
{
  constexpr int BN = (COUT < 128) ? COUT : 128;
  constexpr int NQ = BN / 4;
  constexpr int TY = 256 / NQ;
  constexpr int BM = 32;
  constexpr int MR = BM / TY;
  constexpr int KT = 32;
  constexpr int NCB = COUT / BN;
  constexpr int NRT = MAXP / BM;
  constexpr int NT_C = CIN / KT;
  constexpr int NG = (NV / BM) * NCB;
  constexpr int WLPT = (KT * NQ) / 256;
  constexpr int SLOTCAP = (int)(PBUDGET / ((size_t)COUT * 4));
  __shared__ float as[BM][KT + 1];
  __shared__ float ws[KT][BN];

  const int tid = threadIdx.x;
  const int cq = tid % NQ;
  const int ty = tid / NQ;
  const int la_r = tid >> 3;
  const int la_q = tid & 7;

  bool po;
  int row0, col0, m, sbase = 0, o = 0;
  if (blockIdx.x < NG) {
    po = false;
    const int rb = blockIdx.x / NCB, cb = blockIdx.x - rb * NCB;
    row0 = rb * BM; col0 = cb * BN; m = BM;
  } else {
    po = true;
    int bid = blockIdx.x - NG;
    o = bid / (NRT * NCB);
    int rem = bid - o * (NRT * NCB);
    const int rt = rem / NCB;
    const int cb = rem - rt * NCB;
    m = min(ocnt[o], MAXP);
    row0 = rt * BM;
    if (m == 0 || row0 >= m) return;
    sbase = obase[o]; col0 = cb * BN;
  }

  const float* __restrict__ fW = Wall + (size_t)(po ? o : ctr) * (CIN*COUT) + col0;
  int grow;
  if (!po) grow = row0 + la_r;
  else { const int pA = row0 + la_r; grow = olist[o*MAXP + ((pA < m) ? pA : row0)] & 0xFFF; }
  const float* __restrict__ fA = f + (size_t)grow * CIN + la_q * 4;

  float4 aP, wP[WLPT];
  aP = *(const float4*)&fA[0];
  #pragma unroll
  for (int i = 0; i < WLPT; ++i) {
    const int idx = tid + i*256, k = idx / NQ, q = idx - k*NQ;
    wP[i] = *(const float4*)&fW[(size_t)k * COUT + q*4];
  }

  float4 acc[MR];
  #pragma unroll
  for (int i = 0; i < MR; ++i) { acc[i].x=0.f; acc[i].y=0.f; acc[i].z=0.f; acc[i].w=0.f; }

  for (int t = 0; t < NT_C; ++t) {
    as[la_r][la_q*4+0] = aP.x;
    as[la_r][la_q*4+1] = aP.y;
    as[la_r][la_q*4+2] = aP.z;
    as[la_r][la_q*4+3] = aP.w;
    #pragma unroll
    for (int i = 0; i < WLPT; ++i) {
      const int idx = tid + i*256, k = idx / NQ, q = idx - k*NQ;
      *(float4*)&ws[k][q*4] = wP[i];
    }
    __syncthreads();
    if (t + 1 < NT_C) {
      const int k0 = (t + 1) * KT;
      aP = *(const float4*)&fA[k0];
      #pragma unroll
      for (int i = 0; i < WLPT; ++i) {
        const int idx = tid + i*256, k = idx / NQ, q = idx - k*NQ;
        wP[i] = *(const float4*)&fW[(size_t)(k0 + k) * COUT + q*4];
      }
    }
    #pragma unroll
    for (int k = 0; k < KT; ++k) {
      const float4 wv = *(const float4*)&ws[k][cq*4];
      #pragma unroll
      for (int i = 0; i < MR; ++i) {
        const float av = as[ty*MR + i][k];
        acc[i].x = fmaf(av, wv.x, acc[i].x);
        acc[i].y = fmaf(av, wv.y, acc[i].y);
        acc[i].z = fmaf(av, wv.z, acc[i].z);
        acc[i].w = fmaf(av, wv.w, acc[i].w);
      }
    }
    __syncthreads();
  }
  if (!po) {
    #pragma unroll
    for (int i = 0; i < MR; ++i)
      *(float4*)&outC[(size_t)(row0 + ty*MR + i) * COUT + col0 + cq*4] = acc[i];
  } else {
    #pragma unroll
    for (int i = 0; i < MR; ++i) {
      const int p = row0 + ty*MR + i;
      const int slot = sbase + p;
      if (p < m && slot < SLOTCAP)
        *(float4*)&P[(size_t)slot * COUT + col0 + cq*4] = acc[i];
    }
  }
}

// ---------------- stage-0 conv-a (CIN==1) ----------------
template<int COUT>
__global__ __launch_bounds__(256) void k_cgemm1(const float* __restrict__ f,
    const float* __restrict__ Wall, int ctr,
    float* __restrict__ outC, float* __restrict__ P,
    const int* __restrict__ ocnt, const int* __restrict__ obase,
    const int* __restrict__ olist)
{
  constexpr int NG = NV * COUT / 256;
  constexpr int SLOTCAP = (int)(PBUDGET / ((size_t)COUT * 4));
  const int tid = threadIdx.x;
  if (blockIdx.x < NG) {
    const int idx = blockIdx.x * 256 + tid;
    const int i = idx / COUT, c = idx - i * COUT;
    outC[idx] = f[i] * Wall[(size_t)ctr * COUT + c];
  } else {
    const int o = blockIdx.x - NG;
    int m = ocnt[o];
    if (m == 0) return;
    if (m > MAXP) m = MAXP;
    const int sbase = obase[o];
    const float* __restrict__ Wo = Wall + (size_t)o * COUT;
    for (int p = 0; p < m; ++p) {
      const int j = olist[o*MAXP + p] & 0xFFF;
      const int slot = sbase + p;
      if (slot < SLOTCAP && tid < COUT)
        P[(size_t)slot*COUT + tid] = f[j] * Wo[tid];
    }
  }
}

// ---------------- fused psum + BN stats + BN-ReLU (+ hash duties) ----------------
template<int COUT, bool POOL>
__global__ __launch_bounds__(256) void k_bn(float* __restrict__ x,
    const float* __restrict__ P, const int* __restrict__ pslot,
    const int* __restrict__ obase, const int* __restrict__ cnt,
    const float* __restrict__ g, const float* __restrict__ b,
    const int* __restrict__ nactp,
    const int* __restrict__ co, long long* __restrict__ pk, float* __restrict__ fY,
    long long* __restrict__ hk, int* __restrict__ hv,
    int sd, int sh, int sw, int oD, int oH, int oW)
{
  constexpr int RPT = NV / 256;
  constexpr int SLOTCAP = (int)(PBUDGET / ((size_t)COUT * 4));
  const int c = blockIdx.x;
  const int tid = threadIdx.x;
  const int nact = *nactp;

  if (!POOL && c < 32) {
    const int i = c * 256 + tid;
    hk[i] = -1LL;
    hv[i] = INT_MAX;
  }
  if (POOL && c < 8) {
    const int i = c * 256 + tid;
    if (i < nact) {
      const int bb = co[i*4+0];
      const int d = co[i*4+1] / sd, h = co[i*4+2] / sh, w = co[i*4+3] / sw;
      const long long key = (((long long)bb*oD + d)*oH + h)*(long long)oW + w;
      pk[i] = key;
      unsigned hs = hashk(key);
      while (true) {
        unsigned long long old = atomicCAS((unsigned long long*)&hk[hs], ~0ull, (unsigned long long)key);
        if (old == ~0ull || (long long)old == key) { atomicMin(&hv[hs], i); break; }
        hs = (hs + 1) & HMASK;
      }
    } else pk[i] = BIGK;
  }

  float v[RPT];
  double s1 = 0.0, s2 = 0.0;
  #pragma unroll
  for (int rr = 0; rr < RPT; ++rr) {
    const int r = rr * 256 + tid;
    float vv = x[(size_t)r * COUT + c];
    if (r < nact) {
      const int n = cnt[r];
      float acc = 0.f;
      for (int h = 0; h < n; ++h) {
        const int e = pslot[r * MAXE + h];
        if (e < 0) continue;
        const int slot = obase[e >> 8] + (e & 0xFF);
        if (slot >= SLOTCAP) continue;
        acc += P[(size_t)slot * COUT + c];
      }
      vv += acc;
    }
    v[rr] = vv;
    s1 += (double)vv;
    s2 += (double)vv * (double)vv;
  }
  __shared__ double r1[256], r2[256];
  __shared__ float ss[2];
  r1[tid] = s1; r2[tid] = s2;
  __syncthreads();
  for (int off = 128; off > 0; off >>= 1) {
    if (tid < off) { r1[tid] += r1[tid + off]; r2[tid] += r2[tid + off]; }
    __syncthreads();
  }
  if (tid == 0) {
    const double n = (double)nact;
    const double mu = r1[0] / n;
    double var = r2[0] / n - mu * mu;
    if (var < 0.0) var = 0.0;
    const double sc = (double)g[c] / sqrt(var + 1e-4);
    ss[0] = (float)sc;
    ss[1] = (float)((double)b[c] - mu * sc);
  }
  __syncthreads();
  const float scale = ss[0], shift = ss[1];
  #pragma unroll
  for (int rr = 0; rr < RPT; ++rr) {
    const int r = rr * 256 + tid;
    float o_ = 0.f;
    if (r < nact) {
      const float y = fmaf(v[rr], scale, shift);
      o_ = (y > 0.f) ? y : 0.f;
    }
    x[(size_t)r * COUT + c] = o_;
    if (POOL) fY[(size_t)r * COUT + c] = 0.f;
  }
}

// ---------------- pool compaction: hash-winner (min site) + prefix-scan rank ----------------
__global__ __launch_bounds__(1024) void k_pcompact(const long long* __restrict__ pk,
    const long long* __restrict__ hk, const int* __restrict__ hv,
    int* __restrict__ cNew, int* __restrict__ map, int* __restrict__ nactOut,
    int D, int H, int Wd)
{
  __shared__ int flag[NV];
  __shared__ int s2[NV];
  __shared__ int rankArr[NV];
  const int t = threadIdx.x;
  const long long k0 = pk[t], k1 = pk[t + 1024];
  int w0 = -1, w1 = -1;
  if (k0 != BIGK) { unsigned h = hashk(k0); while (hk[h] != k0) h = (h + 1) & HMASK; w0 = hv[h]; }
  if (k1 != BIGK) { unsigned h = hashk(k1); while (hk[h] != k1) h = (h + 1) & HMASK; w1 = hv[h]; }
  flag[t] = (w0 == t);
  flag[t + 1024] = (w1 == t + 1024);
  __syncthreads();
  for (int d2 = 1; d2 < NV; d2 <<= 1) {
    s2[t]        = flag[t]        + ((t >= d2)        ? flag[t - d2]        : 0);
    s2[t + 1024] = flag[t + 1024] + ((t + 1024 >= d2) ? flag[t + 1024 - d2] : 0);
    __syncthreads();
    flag[t] = s2[t]; flag[t + 1024] = s2[t + 1024];
    __syncthreads();
  }
  if (w0 == t) rankArr[t] = flag[t] - 1;
  if (w1 == t + 1024) rankArr[t + 1024] = flag[t + 1024] - 1;
  __syncthreads();
  if (k0 != BIGK) {
    const int r = rankArr[w0];
    map[t] = r;
    if (w0 == t) {
      const int w = (int)(k0 % Wd);
      long long q = k0 / Wd;
      const int h = (int)(q % H); q /= H;
      const int d = (int)(q % D);
      const int b = (int)(q / D);
      cNew[r*4+0] = b; cNew[r*4+1] = d; cNew[r*4+2] = h; cNew[r*4+3] = w;
    }
  }
  if (k1 != BIGK) {
    const int r = rankArr[w1];
    map[t + 1024] = r;
    if (w1 == t + 1024) {
      const int w = (int)(k1 % Wd);
      long long q = k1 / Wd;
      const int h = (int)(q % H); q /= H;
      const int d = (int)(q % D);
      const int b = (int)(q / D);
      cNew[r*4+0] = b; cNew[r*4+1] = d; cNew[r*4+2] = h; cNew[r*4+3] = w;
    }
  }
  if (t == 0) *nactOut = flag[NV - 1];
}

// ---------------- fused pool-scatter + next-stage hash clear ----------------
template<int C>
__global__ __launch_bounds__(256) void k_pscl(const float* __restrict__ src,
    float* __restrict__ dst, const int* __restrict__ map, const int* __restrict__ nactp,
    long long* __restrict__ hk, int* __restrict__ ocnt)
{
  constexpr int GPS = NV * C / 256;
  if (blockIdx.x < GPS) {
    const int idx = blockIdx.x * 256 + threadIdx.x;
    const int i = idx / C;
    if (i >= *nactp) return;
    atomicMax((unsigned*)&dst[map[i] * C + (idx % C)], __float_as_uint(src[idx]));
  } else {
    const int i = (blockIdx.x - GPS) * 256 + threadIdx.x;
    if (i < HSIZE) hk[i] = -1LL;
    if (i < K3MAX) ocnt[i] = 0;
  }
}

// ---------------- output zero (float4 grid-stride) ----------------
__global__ __launch_bounds__(256) void k_zero_out(float4* __restrict__ out, int n4)
{
  const int stride = gridDim.x * 256;
  float4 z; z.x = 0.f; z.y = 0.f; z.z = 0.f; z.w = 0.f;
  for (int i = blockIdx.x * 256 + threadIdx.x; i < n4; i += stride)
    out[i] = z;
}

// ---------------- final dense scatter ----------------
__global__ __launch_bounds__(256) void k_out(const float* __restrict__ f,
    const int* __restrict__ c, float* __restrict__ out, const int* __restrict__ nactp)
{
  const int idx = blockIdx.x * 256 + threadIdx.x;
  const int i = idx >> 9, ch = idx & 511;
  if (i >= *nactp) return;
  const int b = c[i*4+0], d = c[i*4+1], h = c[i*4+2], w = c[i*4+3];
  out[ (((b*512 + ch)*2 + d)*111 + h)*98 + w ] = f[idx];
}

// ---------------- host orchestration ----------------
template<int K, int CIN, int C>
static void run_stage(hipStream_t stream, int s,
    const float* Wa, const float* Ga, const float* Ba,
    const float* Wb, const float* Gb, const float* Bb,
    float* fX, float* fY, int* cX, int* cY,
    int D, int H, int W, int pd, int ph, int pw, int oD, int oH, int oW,
    long long* hk, int* hv, long long* pkey, int* pslot, int* cnt, int* map,
    int* nact, int* ocnt, int* obase, int* olist, float* P, unsigned short* Wt)
{
  constexpr int K3 = K*K*K;
  constexpr int CTR = K3/2;
  constexpr int NRT  = MAXP / 32;
  const int* na = nact + s;
  int* done = nact + 6;

  k_hinsert<<<NV/256, 256, 0, stream>>>(cX, hk, hv, na, D, H, W);

  if constexpr (C >= 128) {
    constexpr int NCB = C / 128;
    constexpr int NG  = (NV / 32) * NCB;
    constexpr int NWT = K3 * 2 * (C / 32);
    unsigned short* WtB = Wt + (size_t)K3 * C * CIN;
    k_hits<K, CIN, C, true><<<NV/4 + NWT, 256, 0, stream>>>(cX, hk, hv, na, pslot, cnt,
        ocnt, olist, obase, done, D, H, W, Wa, Wb, Wt, WtB);
    k_mgemm<CIN, C><<<NG + K3*NRT*NCB, 256, 0, stream>>>(fX, Wt, CTR, fY, P, ocnt, obase, olist);
    k_bn<C, false><<<C, 256, 0, stream>>>(fY, P, pslot, obase, cnt, Ga, Ba, na,
        cX, pkey, fX, hk, hv, pd, ph, pw, oD, oH, oW);
    k_mgemm<C, C><<<NG + K3*NRT*NCB, 256, 0, stream>>>(fY, WtB, CTR, fX, P, ocnt, obase, olist);
    k_bn<C, true><<<C, 256, 0, stream>>>(fX, P, pslot, obase, cnt, Gb, Bb, na,
        cX, pkey, fY, hk, hv, pd, ph, pw, oD, oH, oW);
  } else {
    k_hits<K, CIN, C, false><<<NV/4, 256, 0, stream>>>(cX, hk, hv, na, pslot, cnt,
        ocnt, olist, obase, done, D, H, W, nullptr, nullptr, nullptr, nullptr);
    k_cgemm1<C><<<NV*C/256 + K3, 256, 0, stream>>>(fX, Wa, CTR, fY, P, ocnt, obase, olist);
    k_bn<C, false><<<C, 256, 0, stream>>>(fY, P, pslot, obase, cnt, Ga, Ba, na,
        cX, pkey, fX, hk, hv, pd, ph, pw, oD, oH, oW);
    k_cgemm<C, C><<<(NV/32) + K3*NRT, 256, 0, stream>>>(fY, Wb, CTR, fX, P, ocnt, obase, olist);
    k_bn<C, true><<<C, 256, 0, stream>>>(fX, P, pslot, obase, cnt, Gb, Bb, na,
        cX, pkey, fY, hk, hv, pd, ph, pw, oD, oH, oW);
  }

  k_pcompact<<<1, 1024, 0, stream>>>(pkey, hk, hv, cY, map, nact + s + 1, oD, oH, oW);
  k_pscl<C><<<NV*C/256 + HSIZE/256, 256, 0, stream>>>(fX, fY, map, na, hk, ocnt);
}

extern "C" void kernel_launch(void* const* d_in, const int* in_sizes, int n_in,
                              void* d_out, int out_size, void* d_ws, size_t ws_size,
                              hipStream_t stream)
{
  const float* vf    = (const float*)d_in[0];
  const int*   coors = (const int*)d_in[1];
  const float *Wl[10], *Gl[10], *Bl[10];
  for (int i = 0; i < 10; ++i) {
    Wl[i] = (const float*)d_in[3 + 3*i];
    Gl[i] = (const float*)d_in[4 + 3*i];
    Bl[i] = (const float*)d_in[5 + 3*i];
  }

  char* p = (char*)d_ws;
  auto alloc = [&](size_t bytes) { char* q = p; p += (bytes + 255) & ~(size_t)255; return q; };
  float*     fB    = (float*)    alloc((size_t)NV*512*4);
  long long* hk    = (long long*)alloc((size_t)HSIZE*8);
  long long* pkey  = (long long*)alloc((size_t)NV*8);
  int*       hv    = (int*)      alloc((size_t)HSIZE*4);
  int*       cA    = (int*)      alloc((size_t)NV*4*4);
  int*       cB    = (int*)      alloc((size_t)NV*4*4);
  int*       pslot = (int*)      alloc((size_t)NV*MAXE*4);
  int*       cnt   = (int*)      alloc((size_t)NV*4);
  int*       map   = (int*)      alloc((size_t)NV*4);
  int*       nact  = (int*)      alloc(8*4);
  int*       ocnt  = (int*)      alloc((size_t)K3MAX*4);
  int*       obase = (int*)      alloc((size_t)K3MAX*4);

  // scratch aliased into d_out (89 MB); all dead before the final zero
  float*          fA    = (float*)d_out;                                    // 4 MB
  int*            olist = (int*)   ((char*)d_out + (size_t)8*1024*1024);    // 351 KB
  unsigned short* Wt    = (unsigned short*)((char*)d_out + (size_t)9*1024*1024);  // 32 MB
  float*          P     = (float*) ((char*)d_out + (size_t)41*1024*1024);   // 48 MB (SLOTCAP-guarded)

  k_init<<<40, 256, 0, stream>>>(vf, coors, cA, fA, nact, hk, ocnt);

  run_stage<7, 1, 64>  (stream, 0, Wl[0],Gl[0],Bl[0], Wl[1],Gl[1],Bl[1],
    fA, fB, cA, cB, 216, 7992, 7056, 3, 3, 3, 72, 2664, 2352,
    hk, hv, pkey, pslot, cnt, map, nact, ocnt, obase, olist, P, Wt);
  run_stage<7, 64, 128>(stream, 1, Wl[2],Gl[2],Bl[2], Wl[3],Gl[3],Bl[3],
    fB, fA, cB, cA, 72, 2664, 2352, 3, 3, 3, 24, 888, 784,
    hk, hv, pkey, pslot, cnt, map, nact, ocnt, obase, olist, P, Wt);
  run_stage<5, 128, 256>(stream, 2, Wl[4],Gl[4],Bl[4], Wl[5],Gl[5],Bl[5],
    fA, fB, cA, cB, 24, 888, 784, 3, 2, 2, 8, 444, 392,
    hk, hv, pkey, pslot, cnt, map, nact, ocnt, obase, olist, P, Wt);
  run_stage<3, 256, 384>(stream, 3, Wl[6],Gl[6],Bl[6], Wl[7],Gl[7],Bl[7],
    fB, fA, cB, cA, 8, 444, 392, 2, 2, 2, 4, 222, 196,
    hk, hv, pkey, pslot, cnt, map, nact, ocnt, obase, olist, P, Wt);
  run_stage<3, 384, 512>(stream, 4, Wl[8],Gl[8],Bl[8], Wl[9],Gl[9],Bl[9],
    fA, fB, cA, cB, 4, 222, 196, 2, 2, 2, 2, 111, 98,
    hk, hv, pkey, pslot, cnt, map, nact, ocnt, obase, olist, P, Wt);

  k_zero_out<<<2048, 256, 0, stream>>>((float4*)d_out, out_size / 4);
  k_out<<<NV*512/256, 256, 0, stream>>>(fB, cB, (float*)d_out, nact + 5);
}

// Round 18
// 556.654 us; speedup vs baseline: 1.0259x; 1.0083x over previous
//
#include <hip/hip_runtime.h>
#include <climits>
#include <cstdint>

#define NV    2048
#define MAXE  344
#define HSIZE 8192
#define HMASK 8191
#define BIGK  LLONG_MAX
#define K3MAX 343
#define MAXP  256
#define PBUDGET (48ull*1024*1024)

typedef __attribute__((ext_vector_type(8))) short bf16x8;
typedef __attribute__((ext_vector_type(4))) float f32x4;

__device__ __forceinline__ unsigned hashk(long long k) {
  unsigned long long x = (unsigned long long)k * 0x9E3779B97F4A7C15ull;
  return (unsigned)(x >> 51) & HMASK;
}

__device__ __forceinline__ unsigned short bfr(float x) {   // fp32 -> bf16 RNE
  unsigned u = __float_as_uint(x);
  u = (u + 0x7FFFu + ((u >> 16) & 1u)) >> 16;
  return (unsigned short)u;
}

// ---------------- init + hash clear (fused) ----------------
__global__ __launch_bounds__(256) void k_init(const float* __restrict__ vf,
    const int* __restrict__ coors, int* __restrict__ cA, float* __restrict__ fA,
    int* __restrict__ nact, long long* __restrict__ hk, int* __restrict__ ocnt)
{
  const int bid = blockIdx.x;
  if (bid < 8) {
    const int i = bid * 256 + threadIdx.x;
    if (i == 0) { nact[0] = NV; nact[6] = 0; }
    if (i >= NV) return;
    cA[i*4+0] = coors[i*4+0];
    cA[i*4+1] = coors[i*4+1];
    cA[i*4+2] = coors[i*4+2];
    cA[i*4+3] = coors[i*4+3];
    fA[i] = vf[i];
  } else {
    const int i = (bid - 8) * 256 + threadIdx.x;
    if (i < HSIZE) hk[i] = -1LL;
    if (i < K3MAX) ocnt[i] = 0;
  }
}

__global__ __launch_bounds__(256) void k_hinsert(const int* __restrict__ c,
    long long* __restrict__ hk, int* __restrict__ hv, const int* __restrict__ nactp,
    int D, int H, int Wd)
{
  int i = blockIdx.x * 256 + threadIdx.x;
  if (i >= NV || i >= *nactp) return;
  long long key = (((long long)c[i*4+0]*D + c[i*4+1])*H + c[i*4+2])*(long long)Wd + c[i*4+3];
  unsigned h = hashk(key);
  while (true) {
    unsigned long long old = atomicCAS((unsigned long long*)&hk[h], ~0ull, (unsigned long long)key);
    if (old == ~0ull) { hv[h] = i; break; }
    h = (h + 1) & HMASK;
  }
}

// ---------------- W transpose slab: 128k x 32c tile, 4 float4 loads/thread ----------------
template<int NK, int CC>
__device__ __forceinline__ void wslab(const float* __restrict__ src,
    unsigned short* __restrict__ dst, int ct, int kb, int tid,
    unsigned short (*__restrict__ tt)[136])
{
  constexpr int KB = (NK < 128) ? NK : 128;
  const int kr = tid >> 3;
  const int c4 = (tid & 7) * 4;
  const int kbase = kb * KB;
  #pragma unroll
  for (int i = 0; i < KB/32; ++i) {
    const int k = kr + i*32;
    const float4 v = *(const float4*)&src[(size_t)(kbase + k) * CC + ct*32 + c4];
    tt[c4+0][k] = bfr(v.x);
    tt[c4+1][k] = bfr(v.y);
    tt[c4+2][k] = bfr(v.z);
    tt[c4+3][k] = bfr(v.w);
  }
  __syncthreads();
  const int cr = tid >> 3;
  const int kq = (tid & 7) * 8;
  unsigned short* __restrict__ drow = dst + (size_t)(ct*32 + cr) * NK + kbase;
  #pragma unroll
  for (int kk = 0; kk < KB; kk += 64) {
    const uint4 v = *(const uint4*)&tt[cr][kk + kq];
    *(uint4*)&drow[kk + kq] = v;
  }
}

// ---------------- neighbor hit lists + fused tail oscan + fused W transpose ----------------
template<int K, int CIN, int C, bool DOWTR>
__global__ __launch_bounds__(256) void k_hits(const int* __restrict__ c,
    const long long* __restrict__ hk, const int* __restrict__ hv,
    const int* __restrict__ nactp, int* __restrict__ pslot, int* __restrict__ cnt,
    int* __restrict__ ocnt, int* __restrict__ olist, int* __restrict__ obase,
    int* __restrict__ done, int D, int H, int Wd,
    const float* __restrict__ Wa, const float* __restrict__ Wb,
    unsigned short* __restrict__ WtA, unsigned short* __restrict__ WtB)
{
  constexpr int K3 = K*K*K, R = K/2, CTR = K3/2;
  constexpr int NVB = NV / 4;
  __shared__ int s[512], s2[512];
  __shared__ int lastf;

  if (blockIdx.x >= NVB) {
    if constexpr (DOWTR) {
      __shared__ unsigned short tt[32][136];
      constexpr int NCT = C / 32;
      constexpr int KBA = (CIN < 128) ? CIN : 128;
      constexpr int KBB = (C < 128) ? C : 128;
      constexpr int NKBA = CIN / KBA;
      constexpr int NKBB = C / KBB;
      constexpr int NBA = K3 * NCT * NKBA;
      int b = blockIdx.x - NVB;
      const int tid = threadIdx.x;
      if (b < NBA) {
        const int o  = b / (NCT * NKBA);
        const int r  = b - o * (NCT * NKBA);
        const int ct = r / NKBA;
        const int kb = r - ct * NKBA;
        wslab<CIN, C>(Wa + (size_t)o * CIN * C, WtA + (size_t)o * C * CIN, ct, kb, tid, tt);
      } else {
        b -= NBA;
        const int o  = b / (NCT * NKBB);
        const int r  = b - o * (NCT * NKBB);
        const int ct = r / NKBB;
        const int kb = r - ct * NKBB;
        wslab<C, C>(Wb + (size_t)o * C * C, WtB + (size_t)o * C * C, ct, kb, tid, tt);
      }
    }
    return;
  }

  const int site = blockIdx.x * 4 + (threadIdx.x >> 6);
  const int lane = threadIdx.x & 63;
  const int nact = *nactp;
  if (site < nact) {
    const int b = c[site*4+0], d = c[site*4+1], hc = c[site*4+2], w = c[site*4+3];
    int base = 0;
    for (int o0 = 0; o0 < K3; o0 += 64) {
      const int o = o0 + lane;
      int j = -1;
      if (o < K3 && o != CTR) {
        const int dz = o/(K*K) - R, dy = (o/K)%K - R, dx = o%K - R;
        const int nd = d+dz, nh = hc+dy, nw = w+dx;
        if (nd >= 0 && nd < D && nh >= 0 && nh < H && nw >= 0 && nw < Wd) {
          const long long key = (((long long)b*D + nd)*H + nh)*(long long)Wd + nw;
          unsigned hs = hashk(key);
          while (true) {
            const long long kk = hk[hs];
            if (kk == -1LL) break;
            if (kk == key) { j = hv[hs]; break; }
            hs = (hs + 1) & HMASK;
          }
        }
      }
      const unsigned long long m = __ballot(j >= 0);
      if (j >= 0) {
        const int pos = __popcll(m & ((1ull << lane) - 1ull));
        const int p = atomicAdd(&ocnt[o], 1);
        int tag = -1;
        if (p < MAXP) { olist[o * MAXP + p] = (site << 12) | j; tag = (o << 8) | p; }
        pslot[site * MAXE + base + pos] = tag;
      }
      base += __popcll(m);
    }
    if (lane == 0) cnt[site] = base;
  } else if (lane == 0) cnt[site] = 0;

  __syncthreads();
  if (threadIdx.x == 0) {
    __threadfence();
    lastf = (atomicAdd(done, 1) == NVB - 1) ? 1 : 0;
  }
  __syncthreads();
  if (!lastf) return;
  const int t = threadIdx.x;
  const int v0 = (t < K3MAX) ? min(ocnt[t], MAXP) : 0;
  const int v1 = (t + 256 < K3MAX) ? min(ocnt[t + 256], MAXP) : 0;
  s[t] = v0; s[t + 256] = v1;
  __syncthreads();
  for (int d2 = 1; d2 < 512; d2 <<= 1) {
    s2[t]       = s[t]       + ((t >= d2)       ? s[t - d2]       : 0);
    s2[t + 256] = s[t + 256] + ((t + 256 >= d2) ? s[t + 256 - d2] : 0);
    __syncthreads();
    s[t] = s2[t]; s[t + 256] = s2[t + 256];
    __syncthreads();
  }
  if (t < K3MAX) obase[t] = s[t] - v0;
  if (t + 256 < K3MAX) obase[t + 256] = s[t + 256] - v1;
  if (t == 0) *done = 0;
}

// ---------------- MFMA bf16 fused center + per-offset gather GEMM ----------------
template<int CIN, int COUT>
__global__ __launch_bounds__(256) void k_mgemm(const float* __restrict__ f,
    const unsigned short* __restrict__ Wt, int ctr,
    float* __restrict__ outC, float* __restrict__ P,
    const int* __restrict__ ocnt, const int* __restrict__ obase,
    const int* __restrict__ olist)
{
  constexpr int BM = 32, BN = 128, KT = 32;
  constexpr int NCB = COUT / BN;
  constexpr int NRT = MAXP / BM;
  constexpr int NT  = CIN / KT;
  constexpr int NG  = (NV / BM) * NCB;
  constexpr int SLOTCAP = (int)(PBUDGET / ((size_t)COUT * 4));
  __shared__ unsigned short as2[BM][40];
  __shared__ unsigned short ws2[BN][40];

  const int tid  = threadIdx.x;
  const int wave = tid >> 6;
  const int lane = tid & 63;

  bool po;
  int row0, col0, m, sbase = 0, o = 0;
  if (blockIdx.x < NG) {
    po = false;
    const int rb = blockIdx.x / NCB, cb = blockIdx.x - rb * NCB;
    row0 = rb * BM; col0 = cb * BN; m = BM;
  } else {
    po = true;
    int bid = blockIdx.x - NG;
    o = bid / (NRT * NCB);
    int rem = bid - o * (NRT * NCB);
    const int rt = rem / NCB;
    const int cb = rem - rt * NCB;
    m = min(ocnt[o], MAXP);
    row0 = rt * BM;
    if (m == 0 || row0 >= m) return;
    sbase = obase[o]; col0 = cb * BN;
  }

  const int la_r = tid >> 3;
  const int la_k = (tid & 7) * 4;
  int grow;
  if (!po) grow = row0 + la_r;
  else { const int pA = row0 + la_r; grow = olist[o*MAXP + ((pA < m) ? pA : row0)] & 0xFFF; }
  const float* __restrict__ fA = f + (size_t)grow * CIN + la_k;

  const int wl_c = tid >> 1;
  const int wl_h = (tid & 1) * 16;
  const unsigned short* __restrict__ wbase =
      Wt + ((size_t)(po ? o : ctr) * COUT + col0 + wl_c) * CIN + wl_h;

  const int r0 = (wave & 1) * 16;
  const int c0 = (wave >> 1) * 64;
  const int lr = lane >> 4;
  const int lc = lane & 15;
  const int koff = lr * 8;

  f32x4 acc[4];
  #pragma unroll
  for (int fi = 0; fi < 4; ++fi) acc[fi] = (f32x4){0.f, 0.f, 0.f, 0.f};

  for (int t = 0; t < NT; ++t) {
    const int k0 = t * KT;
    {
      const float4 av = *(const float4*)&fA[k0];
      unsigned short* d = &as2[la_r][la_k];
      d[0] = bfr(av.x); d[1] = bfr(av.y); d[2] = bfr(av.z); d[3] = bfr(av.w);
      const uint4 w0 = *(const uint4*)&wbase[k0];
      const uint4 w1 = *(const uint4*)&wbase[k0 + 8];
      *(uint4*)&ws2[wl_c][wl_h]     = w0;
      *(uint4*)&ws2[wl_c][wl_h + 8] = w1;
    }
    __syncthreads();
    const bf16x8 a = *(const bf16x8*)&as2[r0 + lc][koff];
    #pragma unroll
    for (int fi = 0; fi < 4; ++fi) {
      const bf16x8 b = *(const bf16x8*)&ws2[c0 + fi*16 + lc][koff];
      acc[fi] = __builtin_amdgcn_mfma_f32_16x16x32_bf16(a, b, acc[fi], 0, 0, 0);
    }
    __syncthreads();
  }

  #pragma unroll
  for (int fi = 0; fi < 4; ++fi) {
    const int col = col0 + c0 + fi*16 + lc;
    #pragma unroll
    for (int i = 0; i < 4; ++i) {
      const int rloc = r0 + lr*4 + i;
      if (!po) {
        outC[(size_t)(row0 + rloc) * COUT + col] = acc[fi][i];
      } else {
        const int p = row0 + rloc;
        const int slot = sbase + p;
        if (p < m && slot < SLOTCAP)
          P[(size_t)slot * COUT + col] = acc[fi][i];
      }
    }
  }
}

// ---------------- fp32 fused GEMM (stage 0 conv-b only, C=64) ----------------
template<int CIN, int COUT>
__global__ __launch_bounds__(256) void k_cgemm(const float* __restrict__ f,
    const float* __restrict__ Wall, int ctr,
    float* __restrict__ outC, float* __restrict__ P,
    const int* __restrict__ ocnt, const int* __restrict__ obase,
    const int* __restrict__ olist)
{
  constexpr int BN = (COUT < 128) ? COUT : 128;
  constexpr int NQ = BN / 4;
  constexpr int TY = 256 / NQ;
  constexpr int BM = 32;
  constexpr int MR = BM / TY;
  constexpr int KT = 32;
  constexpr int NCB = COUT / BN;
  constexpr int NRT = MAXP / BM;
  constexpr int NT_C = CIN / KT;
  constexpr int NG = (NV / BM) * NCB;
  constexpr int WLPT = (KT * NQ) / 256;
  constexpr int SLOTCAP = (int)(PBUDGET / ((size_t)COUT * 4));
  __shared__ float as[BM][KT + 1];
  __shared__ float ws[KT][BN];

  const int tid = threadIdx.x;
  const int cq = tid % NQ;
  const int ty = tid / NQ;
  const int la_r = tid >> 3;
  const int la_q = tid & 7;

  bool po;
  int row0, col0, m, sbase = 0, o = 0;
  if (blockIdx.x < NG) {
    po = false;
    const int rb = blockIdx.x / NCB, cb = blockIdx.x - rb * NCB;
    row0 = rb * BM; col0 = cb * BN; m = BM;
  } else {
    po = true;
    int bid = blockIdx.x - NG;
    o = bid / (NRT * NCB);
    int rem = bid - o * (NRT * NCB);
    const int rt = rem / NCB;
    const int cb = rem - rt * NCB;
    m = min(ocnt[o], MAXP);
    row0 = rt * BM;
    if (m == 0 || row0 >= m) return;
    sbase = obase[o]; col0 = cb * BN;
  }

  const float* __restrict__ fW = Wall + (size_t)(po ? o : ctr) * (CIN*COUT) + col0;
  int grow;
  if (!po) grow = row0 + la_r;
  else { const int pA = row0 + la_r; grow = olist[o*MAXP + ((pA < m) ? pA : row0)] & 0xFFF; }
  const float* __restrict__ fA = f + (size_t)grow * CIN + la_q * 4;

  float4 aP, wP[WLPT];
  aP = *(const float4*)&fA[0];
  #pragma unroll
  for (int i = 0; i < WLPT; ++i) {
    const int idx = tid + i*256, k = idx / NQ, q = idx - k*NQ;
    wP[i] = *(const float4*)&fW[(size_t)k * COUT + q*4];
  }

  float4 acc[MR];
  #pragma unroll
  for (int i = 0; i < MR; ++i) { acc[i].x=0.f; acc[i].y=0.f; acc[i].z=0.f; acc[i].w=0.f; }

  for (int t = 0; t < NT_C; ++t) {
    as[la_r][la_q*4+0] = aP.x;
    as[la_r][la_q*4+1] = aP.y;
    as[la_r][la_q*4+2] = aP.z;
    as[la_r][la_q*4+3] = aP.w;
    #pragma unroll
    for (int i = 0; i < WLPT; ++i) {
      const int idx = tid + i*256, k = idx / NQ, q = idx - k*NQ;
      *(float4*)&ws[k][q*4] = wP[i];
    }
    __syncthreads();
    if (t + 1 < NT_C) {
      const int k0 = (t + 1) * KT;
      aP = *(const float4*)&fA[k0];
      #pragma unroll
      for (int i = 0; i < WLPT; ++i) {
        const int idx = tid + i*256, k = idx / NQ, q = idx - k*NQ;
        wP[i] = *(const float4*)&fW[(size_t)(k0 + k) * COUT + q*4];
      }
    }
    #pragma unroll
    for (int k = 0; k < KT; ++k) {
      const float4 wv = *(const float4*)&ws[k][cq*4];
      #pragma unroll
      for (int i = 0; i < MR; ++i) {
        const float av = as[ty*MR + i][k];
        acc[i].x = fmaf(av, wv.x, acc[i].x);
        acc[i].y = fmaf(av, wv.y, acc[i].y);
        acc[i].z = fmaf(av, wv.z, acc[i].z);
        acc[i].w = fmaf(av, wv.w, acc[i].w);
      }
    }
    __syncthreads();
  }
  if (!po) {
    #pragma unroll
    for (int i = 0; i < MR; ++i)
      *(float4*)&outC[(size_t)(row0 + ty*MR + i) * COUT + col0 + cq*4] = acc[i];
  } else {
    #pragma unroll
    for (int i = 0; i < MR; ++i) {
      const int p = row0 + ty*MR + i;
      const int slot = sbase + p;
      if (p < m && slot < SLOTCAP)
        *(float4*)&P[(size_t)slot * COUT + col0 + cq*4] = acc[i];
    }
  }
}

// ---------------- stage-0 conv-a (CIN==1) ----------------
template<int COUT>
__global__ __launch_bounds__(256) void k_cgemm1(const float* __restrict__ f,
    const float* __restrict__ Wall, int ctr,
    float* __restrict__ outC, float* __restrict__ P,
    const int* __restrict__ ocnt, const int* __restrict__ obase,
    const int* __restrict__ olist)
{
  constexpr int NG = NV * COUT / 256;
  constexpr int SLOTCAP = (int)(PBUDGET / ((size_t)COUT * 4));
  const int tid = threadIdx.x;
  if (blockIdx.x < NG) {
    const int idx = blockIdx.x * 256 + tid;
    const int i = idx / COUT, c = idx - i * COUT;
    outC[idx] = f[i] * Wall[(size_t)ctr * COUT + c];
  } else {
    const int o = blockIdx.x - NG;
    int m = ocnt[o];
    if (m == 0) return;
    if (m > MAXP) m = MAXP;
    const int sbase = obase[o];
    const float* __restrict__ Wo = Wall + (size_t)o * COUT;
    for (int p = 0; p < m; ++p) {
      const int j = olist[o*MAXP + p] & 0xFFF;
      const int slot = sbase + p;
      if (slot < SLOTCAP && tid < COUT)
        P[(size_t)slot*COUT + tid] = f[j] * Wo[tid];
    }
  }
}

// ---------------- fused psum + BN stats + BN-ReLU (+ hash duties) ----------------
template<int COUT, bool POOL>
__global__ __launch_bounds__(256) void k_bn(float* __restrict__ x,
    const float* __restrict__ P, const int* __restrict__ pslot,
    const int* __restrict__ obase, const int* __restrict__ cnt,
    const float* __restrict__ g, const float* __restrict__ b,
    const int* __restrict__ nactp,
    const int* __restrict__ co, long long* __restrict__ pk, float* __restrict__ fY,
    long long* __restrict__ hk, int* __restrict__ hv,
    int sd, int sh, int sw, int oD, int oH, int oW)
{
  constexpr int RPT = NV / 256;
  constexpr int SLOTCAP = (int)(PBUDGET / ((size_t)COUT * 4));
  const int c = blockIdx.x;
  const int tid = threadIdx.x;
  const int nact = *nactp;

  if (!POOL && c < 32) {
    const int i = c * 256 + tid;
    hk[i] = -1LL;
    hv[i] = INT_MAX;
  }
  if (POOL && c < 8) {
    const int i = c * 256 + tid;
    if (i < nact) {
      const int bb = co[i*4+0];
      const int d = co[i*4+1] / sd, h = co[i*4+2] / sh, w = co[i*4+3] / sw;
      const long long key = (((long long)bb*oD + d)*oH + h)*(long long)oW + w;
      pk[i] = key;
      unsigned hs = hashk(key);
      while (true) {
        unsigned long long old = atomicCAS((unsigned long long*)&hk[hs], ~0ull, (unsigned long long)key);
        if (old == ~0ull || (long long)old == key) { atomicMin(&hv[hs], i); break; }
        hs = (hs + 1) & HMASK;
      }
    } else pk[i] = BIGK;
  }

  float v[RPT];
  double s1 = 0.0, s2 = 0.0;
  #pragma unroll
  for (int rr = 0; rr < RPT; ++rr) {
    const int r = rr * 256 + tid;
    float vv = x[(size_t)r * COUT + c];
    if (r < nact) {
      const int n = cnt[r];
      float acc = 0.f;
      for (int h = 0; h < n; ++h) {
        const int e = pslot[r * MAXE + h];
        if (e < 0) continue;
        const int slot = obase[e >> 8] + (e & 0xFF);
        if (slot >= SLOTCAP) continue;
        acc += P[(size_t)slot * COUT + c];
      }
      vv += acc;
    }
    v[rr] = vv;
    s1 += (double)vv;
    s2 += (double)vv * (double)vv;
  }
  __shared__ double r1[256], r2[256];
  __shared__ float ss[2];
  r1[tid] = s1; r2[tid] = s2;
  __syncthreads();
  for (int off = 128; off > 0; off >>= 1) {
    if (tid < off) { r1[tid] += r1[tid + off]; r2[tid] += r2[tid + off]; }
    __syncthreads();
  }
  if (tid == 0) {
    const double n = (double)nact;
    const double mu = r1[0] / n;
    double var = r2[0] / n - mu * mu;
    if (var < 0.0) var = 0.0;
    const double sc = (double)g[c] / sqrt(var + 1e-4);
    ss[0] = (float)sc;
    ss[1] = (float)((double)b[c] - mu * sc);
  }
  __syncthreads();
  const float scale = ss[0], shift = ss[1];
  #pragma unroll
  for (int rr = 0; rr < RPT; ++rr) {
    const int r = rr * 256 + tid;
    float o_ = 0.f;
    if (r < nact) {
      const float y = fmaf(v[rr], scale, shift);
      o_ = (y > 0.f) ? y : 0.f;
    }
    x[(size_t)r * COUT + c] = o_;
    if (POOL) fY[(size_t)r * COUT + c] = 0.f;
  }
}

// ---------------- pool compaction: hash-winner (min site) + prefix-scan rank ----------------
__global__ __launch_bounds__(1024) void k_pcompact(const long long* __restrict__ pk,
    const long long* __restrict__ hk, const int* __restrict__ hv,
    int* __restrict__ cNew, int* __restrict__ map, int* __restrict__ nactOut,
    int D, int H, int Wd)
{
  __shared__ int flag[NV];
  __shared__ int s2[NV];
  __shared__ int rankArr[NV];
  const int t = threadIdx.x;
  const long long k0 = pk[t], k1 = pk[t + 1024];
  int w0 = -1, w1 = -1;
  if (k0 != BIGK) { unsigned h = hashk(k0); while (hk[h] != k0) h = (h + 1) & HMASK; w0 = hv[h]; }
  if (k1 != BIGK) { unsigned h = hashk(k1); while (hk[h] != k1) h = (h + 1) & HMASK; w1 = hv[h]; }
  flag[t] = (w0 == t);
  flag[t + 1024] = (w1 == t + 1024);
  __syncthreads();
  for (int d2 = 1; d2 < NV; d2 <<= 1) {
    s2[t]        = flag[t]        + ((t >= d2)        ? flag[t - d2]        : 0);
    s2[t + 1024] = flag[t + 1024] + ((t + 1024 >= d2) ? flag[t + 1024 - d2] : 0);
    __syncthreads();
    flag[t] = s2[t]; flag[t + 1024] = s2[t + 1024];
    __syncthreads();
  }
  if (w0 == t) rankArr[t] = flag[t] - 1;
  if (w1 == t + 1024) rankArr[t + 1024] = flag[t + 1024] - 1;
  __syncthreads();
  if (k0 != BIGK) {
    const int r = rankArr[w0];
    map[t] = r;
    if (w0 == t) {
      const int w = (int)(k0 % Wd);
      long long q = k0 / Wd;
      const int h = (int)(q % H); q /= H;
      const int d = (int)(q % D);
      const int b = (int)(q / D);
      cNew[r*4+0] = b; cNew[r*4+1] = d; cNew[r*4+2] = h; cNew[r*4+3] = w;
    }
  }
  if (k1 != BIGK) {
    const int r = rankArr[w1];
    map[t + 1024] = r;
    if (w1 == t + 1024) {
      const int w = (int)(k1 % Wd);
      long long q = k1 / Wd;
      const int h = (int)(q % H); q /= H;
      const int d = (int)(q % D);
      const int b = (int)(q / D);
      cNew[r*4+0] = b; cNew[r*4+1] = d; cNew[r*4+2] = h; cNew[r*4+3] = w;
    }
  }
  if (t == 0) *nactOut = flag[NV - 1];
}

// ---------------- fused pool-scatter + next-stage hash clear ----------------
template<int C>
__global__ __launch_bounds__(256) void k_pscl(const float* __restrict__ src,
    float* __restrict__ dst, const int* __restrict__ map, const int* __restrict__ nactp,
    long long* __restrict__ hk, int* __restrict__ ocnt)
{
  constexpr int GPS = NV * C / 256;
  if (blockIdx.x < GPS) {
    const int idx = blockIdx.x * 256 + threadIdx.x;
    const int i = idx / C;
    if (i >= *nactp) return;
    atomicMax((unsigned*)&dst[map[i] * C + (idx % C)], __float_as_uint(src[idx]));
  } else {
    const int i = (blockIdx.x - GPS) * 256 + threadIdx.x;
    if (i < HSIZE) hk[i] = -1LL;
    if (i < K3MAX) ocnt[i] = 0;
  }
}

// ---------------- output zero (float4 grid-stride) ----------------
__global__ __launch_bounds__(256) void k_zero_out(float4* __restrict__ out, int n4)
{
  const int stride = gridDim.x * 256;
  float4 z; z.x = 0.f; z.y = 0.f; z.z = 0.f; z.w = 0.f;
  for (int i = blockIdx.x * 256 + threadIdx.x; i < n4; i += stride)
    out[i] = z;
}

// ---------------- final dense scatter ----------------
__global__ __launch_bounds__(256) void k_out(const float* __restrict__ f,
    const int* __restrict__ c, float* __restrict__ out, const int* __restrict__ nactp)
{
  const int idx = blockIdx.x * 256 + threadIdx.x;
  const int i = idx >> 9, ch = idx & 511;
  if (i >= *nactp) return;
  const int b = c[i*4+0], d = c[i*4+1], h = c[i*4+2], w = c[i*4+3];
  out[ (((b*512 + ch)*2 + d)*111 + h)*98 + w ] = f[idx];
}

// ---------------- host orchestration ----------------
template<int K, int CIN, int C>
static void run_stage(hipStream_t stream, int s,
    const float* Wa, const float* Ga, const float* Ba,
    const float* Wb, const float* Gb, const float* Bb,
    float* fX, float* fY, int* cX, int* cY,
    int D, int H, int W, int pd, int ph, int pw, int oD, int oH, int oW,
    long long* hk, int* hv, long long* pkey, int* pslot, int* cnt, int* map,
    int* nact, int* ocnt, int* obase, int* olist, float* P, unsigned short* Wt)
{
  constexpr int K3 = K*K*K;
  constexpr int CTR = K3/2;
  constexpr int NRT  = MAXP / 32;
  const int* na = nact + s;
  int* done = nact + 6;

  k_hinsert<<<NV/256, 256, 0, stream>>>(cX, hk, hv, na, D, H, W);

  if constexpr (C >= 128) {
    constexpr int NCB = C / 128;
    constexpr int NG  = (NV / 32) * NCB;
    constexpr int NCT = C / 32;
    constexpr int KBA = (CIN < 128) ? CIN : 128;
    constexpr int KBB = (C < 128) ? C : 128;
    constexpr int NKBA = CIN / KBA;
    constexpr int NKBB = C / KBB;
    constexpr int NWT = K3 * NCT * (NKBA + NKBB);
    unsigned short* WtB = Wt + (size_t)K3 * C * CIN;
    k_hits<K, CIN, C, true><<<NV/4 + NWT, 256, 0, stream>>>(cX, hk, hv, na, pslot, cnt,
        ocnt, olist, obase, done, D, H, W, Wa, Wb, Wt, WtB);
    k_mgemm<CIN, C><<<NG + K3*NRT*NCB, 256, 0, stream>>>(fX, Wt, CTR, fY, P, ocnt, obase, olist);
    k_bn<C, false><<<C, 256, 0, stream>>>(fY, P, pslot, obase, cnt, Ga, Ba, na,
        cX, pkey, fX, hk, hv, pd, ph, pw, oD, oH, oW);
    k_mgemm<C, C><<<NG + K3*NRT*NCB, 256, 0, stream>>>(fY, WtB, CTR, fX, P, ocnt, obase, olist);
    k_bn<C, true><<<C, 256, 0, stream>>>(fX, P, pslot, obase, cnt, Gb, Bb, na,
        cX, pkey, fY, hk, hv, pd, ph, pw, oD, oH, oW);
  } else {
    k_hits<K, CIN, C, false><<<NV/4, 256, 0, stream>>>(cX, hk, hv, na, pslot, cnt,
        ocnt, olist, obase, done, D, H, W, nullptr, nullptr, nullptr, nullptr);
    k_cgemm1<C><<<NV*C/256 + K3, 256, 0, stream>>>(fX, Wa, CTR, fY, P, ocnt, obase, olist);
    k_bn<C, false><<<C, 256, 0, stream>>>(fY, P, pslot, obase, cnt, Ga, Ba, na,
        cX, pkey, fX, hk, hv, pd, ph, pw, oD, oH, oW);
    k_cgemm<C, C><<<(NV/32) + K3*NRT, 256, 0, stream>>>(fY, Wb, CTR, fX, P, ocnt, obase, olist);
    k_bn<C, true><<<C, 256, 0, stream>>>(fX, P, pslot, obase, cnt, Gb, Bb, na,
        cX, pkey, fY, hk, hv, pd, ph, pw, oD, oH, oW);
  }

  k_pcompact<<<1, 1024, 0, stream>>>(pkey, hk, hv, cY, map, nact + s + 1, oD, oH, oW);
  k_pscl<C><<<NV*C/256 + HSIZE/256, 256, 0, stream>>>(fX, fY, map, na, hk, ocnt);
}

extern "C" void kernel_launch(void* const* d_in, const int* in_sizes, int n_in,
                              void* d_out, int out_size, void* d_ws, size_t ws_size,
                              hipStream_t stream)
{
  const float* vf    = (const float*)d_in[0];
  const int*   coors = (const int*)d_in[1];
  const float *Wl[10], *Gl[10], *Bl[10];
  for (int i = 0; i < 10; ++i) {
    Wl[i] = (const float*)d_in[3 + 3*i];
    Gl[i] = (const float*)d_in[4 + 3*i];
    Bl[i] = (const float*)d_in[5 + 3*i];
  }

  char* p = (char*)d_ws;
  auto alloc = [&](size_t bytes) { char* q = p; p += (bytes + 255) & ~(size_t)255; return q; };
  float*     fB    = (float*)    alloc((size_t)NV*512*4);
  long long* hk    = (long long*)alloc((size_t)HSIZE*8);
  long long* pkey  = (long long*)alloc((size_t)NV*8);
  int*       hv    = (int*)      alloc((size_t)HSIZE*4);
  int*       cA    = (int*)      alloc((size_t)NV*4*4);
  int*       cB    = (int*)      alloc((size_t)NV*4*4);
  int*       pslot = (int*)      alloc((size_t)NV*MAXE*4);
  int*       cnt   = (int*)      alloc((size_t)NV*4);
  int*       map   = (int*)      alloc((size_t)NV*4);
  int*       nact  = (int*)      alloc(8*4);
  int*       ocnt  = (int*)      alloc((size_t)K3MAX*4);
  int*       obase = (int*)      alloc((size_t)K3MAX*4);

  // scratch aliased into d_out (89 MB); all dead before the final zero
  float*          fA    = (float*)d_out;                                    // 4 MB
  int*            olist = (int*)   ((char*)d_out + (size_t)8*1024*1024);    // 351 KB
  unsigned short* Wt    = (unsigned short*)((char*)d_out + (size_t)9*1024*1024);  // 32 MB
  float*          P     = (float*) ((char*)d_out + (size_t)41*1024*1024);   // 48 MB (SLOTCAP-guarded)

  k_init<<<40, 256, 0, stream>>>(vf, coors, cA, fA, nact, hk, ocnt);

  run_stage<7, 1, 64>  (stream, 0, Wl[0],Gl[0],Bl[0], Wl[1],Gl[1],Bl[1],
    fA, fB, cA, cB, 216, 7992, 7056, 3, 3, 3, 72, 2664, 2352,
    hk, hv, pkey, pslot, cnt, map, nact, ocnt, obase, olist, P, Wt);
  run_stage<7, 64, 128>(stream, 1, Wl[2],Gl[2],Bl[2], Wl[3],Gl[3],Bl[3],
    fB, fA, cB, cA, 72, 2664, 2352, 3, 3, 3, 24, 888, 784,
    hk, hv, pkey, pslot, cnt, map, nact, ocnt, obase, olist, P, Wt);
  run_stage<5, 128, 256>(stream, 2, Wl[4],Gl[4],Bl[4], Wl[5],Gl[5],Bl[5],
    fA, fB, cA, cB, 24, 888, 784, 3, 2, 2, 8, 444, 392,
    hk, hv, pkey, pslot, cnt, map, nact, ocnt, obase, olist, P, Wt);
  run_stage<3, 256, 384>(stream, 3, Wl[6],Gl[6],Bl[6], Wl[7],Gl[7],Bl[7],
    fB, fA, cB, cA, 8, 444, 392, 2, 2, 2, 4, 222, 196,
    hk, hv, pkey, pslot, cnt, map, nact, ocnt, obase, olist, P, Wt);
  run_stage<3, 384, 512>(stream, 4, Wl[8],Gl[8],Bl[8], Wl[9],Gl[9],Bl[9],
    fA, fB, cA, cB, 4, 222, 196, 2, 2, 2, 2, 111, 98,
    hk, hv, pkey, pslot, cnt, map, nact, ocnt, obase, olist, P, Wt);

  k_zero_out<<<2048, 256, 0, stream>>>((float4*)d_out, out_size / 4);
  k_out<<<NV*512/256, 256, 0, stream>>>(fB, cB, (float*)d_out, nact + 5);
}